// Round 9
// baseline (809.535 us; speedup 1.0000x reference)
//
#include <hip/hip_runtime.h>

typedef __bf16 bf16;
typedef __bf16 bf16x8 __attribute__((ext_vector_type(8)));
typedef float  f32x4  __attribute__((ext_vector_type(4)));

#define NB 4
#define NT 2048
#define NC 512
#define NV 32000
#define NROWS (NB*NT)          // 8192
#define NCHUNK 250             // 128-col chunks for LM-head partials
#define LNEPS 1e-5f
#define SMEM_B 131072

static __device__ __forceinline__ void load_lds16(const bf16* g, char* l) {
  __builtin_amdgcn_global_load_lds(
      (const __attribute__((address_space(1))) void*)g,
      (__attribute__((address_space(3))) void*)l, 16, 0, 0);
}

static __device__ __forceinline__ void bar() {
  asm volatile("" ::: "memory");
  __builtin_amdgcn_s_barrier();
  asm volatile("" ::: "memory");
}

// ---------------- f32 -> bf16 convert ----------------
__global__ __launch_bounds__(256)
void cvt_kernel(const float* __restrict__ in, bf16* __restrict__ out, int n8) {
  long i = (long)blockIdx.x * 256 + threadIdx.x;
  long stride = (long)gridDim.x * 256;
  for (; i < n8; i += stride) {
    const float* p = in + i * 8;
    f32x4 a = *(const f32x4*)p;
    f32x4 b = *(const f32x4*)(p + 4);
    bf16x8 o;
    o[0]=(bf16)a.x; o[1]=(bf16)a.y; o[2]=(bf16)a.z; o[3]=(bf16)a.w;
    o[4]=(bf16)b.x; o[5]=(bf16)b.y; o[6]=(bf16)b.z; o[7]=(bf16)b.w;
    *(bf16x8*)(out + i*8) = o;
  }
}

// ---------------- fused embedding + layernorm1 ----------------
__global__ __launch_bounds__(64)
void embed_ln_kernel(const int* __restrict__ idx, const float* __restrict__ tok,
                     const float* __restrict__ pos, const float* __restrict__ gw,
                     const float* __restrict__ bw,
                     float* __restrict__ x0, bf16* __restrict__ h1) {
  int row = blockIdx.x;
  int t = row & (NT-1);
  int id = idx[row];
  int lane = threadIdx.x;
  const float* tr = tok + (long)id*NC + lane*8;
  const float* pr = pos + (long)t*NC + lane*8;
  f32x4 a0 = *(const f32x4*)tr, a1 = *(const f32x4*)(tr+4);
  f32x4 p0 = *(const f32x4*)pr, p1 = *(const f32x4*)(pr+4);
  f32x4 r0 = a0 + p0, r1 = a1 + p1;
  float* o = x0 + (long)row*NC + lane*8;
  *(f32x4*)o = r0; *(f32x4*)(o+4) = r1;
  float v[8] = {r0.x,r0.y,r0.z,r0.w,r1.x,r1.y,r1.z,r1.w};
  float s = 0.f;
  #pragma unroll
  for (int j=0;j<8;++j) s += v[j];
  #pragma unroll
  for (int m=32;m>=1;m>>=1) s += __shfl_xor(s, m);
  float mu = s * (1.f/NC);
  float sq = 0.f;
  #pragma unroll
  for (int j=0;j<8;++j) { v[j] -= mu; sq += v[j]*v[j]; }
  #pragma unroll
  for (int m=32;m>=1;m>>=1) sq += __shfl_xor(sq, m);
  float rs = rsqrtf(sq * (1.f/NC) + LNEPS);
  const float* gp = gw + lane*8;
  const float* bp = bw + lane*8;
  f32x4 g0 = *(const f32x4*)gp, g1 = *(const f32x4*)(gp+4);
  f32x4 b0 = *(const f32x4*)bp, b1 = *(const f32x4*)(bp+4);
  float gg[8] = {g0.x,g0.y,g0.z,g0.w,g1.x,g1.y,g1.z,g1.w};
  float bb[8] = {b0.x,b0.y,b0.z,b0.w,b1.x,b1.y,b1.z,b1.w};
  bf16x8 oo;
  #pragma unroll
  for (int j=0;j<8;++j) oo[j] = (bf16)(v[j]*rs*gg[j] + bb[j]);
  *(bf16x8*)(h1 + (long)row*NC + lane*8) = oo;
}

// ---------------- transpose v[b][t][c] (stride ldv) -> vt[b][c][t] ----------------
__global__ __launch_bounds__(256)
void transpose_kernel(const bf16* __restrict__ v, long ldv, bf16* __restrict__ vt) {
  __shared__ bf16 tile[64][66];
  int b = blockIdx.z;
  int t0 = blockIdx.x*64, c0 = blockIdx.y*64;
  int tid = threadIdx.x;
  int r = tid >> 2, ch = (tid & 3) * 16;
  const bf16* src = v + ((long)b*NT + t0 + r)*ldv + c0 + ch;
  #pragma unroll
  for (int i=0;i<16;++i) tile[r][ch+i] = src[i];
  __syncthreads();
  bf16x8 o0, o1;
  #pragma unroll
  for (int i=0;i<8;++i) o0[i] = tile[ch+i][r];
  #pragma unroll
  for (int i=0;i<8;++i) o1[i] = tile[ch+8+i][r];
  bf16* dst = vt + ((long)b*NC + c0 + r)*NT + t0 + ch;
  *(bf16x8*)dst = o0;
  *(bf16x8*)(dst+8) = o1;
}

// ---------------- causal softmax row: S f32 -> P bf16 (aliased into S) ----------------
__global__ __launch_bounds__(256)
void softmax_kernel(float* __restrict__ S) {
  const int row = blockIdx.x;
  const int t = row & (NT-1);
  const int tid = threadIdx.x;
  float* sr = S + (long)row*NT;
  bf16* pr = (bf16*)S + (long)row*(2*NT);
  const float scale = 0.044194173824159216f;
  f32x4 v0 = *(const f32x4*)(sr + tid*8);
  f32x4 v1 = *(const f32x4*)(sr + tid*8 + 4);
  float v[8] = {v0.x,v0.y,v0.z,v0.w,v1.x,v1.y,v1.z,v1.w};
  int cb = tid*8;
  float mx = -1e30f;
  #pragma unroll
  for (int j=0;j<8;++j) {
    v[j] = (cb + j <= t) ? v[j]*scale : -1e30f;
    mx = fmaxf(mx, v[j]);
  }
  __shared__ float redm[4];
  #pragma unroll
  for (int m=32;m>=1;m>>=1) mx = fmaxf(mx, __shfl_xor(mx, m));
  if ((tid & 63) == 0) redm[tid>>6] = mx;
  __syncthreads();
  mx = fmaxf(fmaxf(redm[0],redm[1]), fmaxf(redm[2],redm[3]));
  float e[8]; float s = 0.f;
  #pragma unroll
  for (int j=0;j<8;++j) { e[j] = (cb + j <= t) ? __expf(v[j]-mx) : 0.f; s += e[j]; }
  __shared__ float reds[4];
  #pragma unroll
  for (int m=32;m>=1;m>>=1) s += __shfl_xor(s, m);
  if ((tid & 63) == 0) reds[tid>>6] = s;
  __syncthreads();
  s = reds[0]+reds[1]+reds[2]+reds[3];
  float inv = 1.f/s;
  bf16x8 o;
  #pragma unroll
  for (int j=0;j<8;++j) o[j] = (bf16)(e[j]*inv);
  *(bf16x8*)(pr + cb) = o;
}

// ======== 256x256-tile 8-phase GEMM: out[M,N] = A[M,K] * B[N,K]^T ========
enum { EPI_F32=0, EPI_BF16=1, EPI_BIAS_RELU_BF16=2, EPI_BIAS_RES_BF16=3, EPI_RES_F32=4 };

template<int EPI, bool CAUSAL=false, bool SWAP=false, bool KCHUNK=false>
__global__ __launch_bounds__(512,2)
void gemm256(const bf16* __restrict__ A, const bf16* __restrict__ B, int nkt,
             long lda, long ldb, long sAb, long sBb,
             float* __restrict__ outf, bf16* __restrict__ outb, long ldo, long sOb,
             const float* __restrict__ bias,
             const float* __restrict__ res, long ldr, long sRb) {
  extern __shared__ char smem[];
  int bn, bm;
  if constexpr (SWAP) { bm = blockIdx.x; bn = blockIdx.y; }
  else               { bn = blockIdx.x; bm = blockIdx.y; }
  const int bz = blockIdx.z;
  if constexpr (CAUSAL) { if (bn > bm) return; }
  int nkt_eff = nkt;
  int bzAB = bz;
  long kOff = 0;
  if constexpr (KCHUNK) {
    int c = bz >> 2; bzAB = bz & 3;
    int lim = (bm+1)*4 - c*8;
    if (lim <= 0) return;
    if (lim < nkt_eff) nkt_eff = lim;
    kOff = (long)c*512;
  }

  const int tid = threadIdx.x;
  const int wid = tid >> 6, lane = tid & 63;
  const int wr = wid >> 2, wc = wid & 3;
  const int l15 = lane & 15, g = lane >> 4;

  const bf16* Ab = A + (long)bzAB*sAb + kOff + (long)bm*256*lda;
  const bf16* Bb = B + (long)bzAB*sBb + kOff + (long)bn*256*ldb;

  const int colsw = 8 * ((tid & 7) ^ ((tid >> 3) & 7));
  const bf16* A0 = Ab + (long)(tid >> 3)*lda + colsw;
  const bf16* B0 = Bb + (long)(tid >> 3)*ldb + colsw;

  auto stage = [&](int ab, int t, int h, int slot) {
    char* dst = smem + slot*65536 + ab*32768 + h*16384 + wid*1024;
    const bf16* s0 = (ab ? B0 : A0) + (long)(h*128)*(ab ? ldb : lda) + (long)t*64;
    load_lds16(s0, dst);
    load_lds16(s0 + 64*(ab ? ldb : lda), dst + 8192);
  };

  const char* sm = smem;
  auto aLoad = [&](int slot, int m, int kk) -> bf16x8 {
    int row = m*16 + l15;
    int b = row*128 + ((kk*64 + g*16) ^ ((row & 7) << 4));
    return *(const bf16x8*)(sm + slot*65536 + wr*16384 + b);
  };
  auto bLoad = [&](int slot, int n, int kk) -> bf16x8 {
    int row = (wc & 1)*64 + n*16 + l15;
    int b = row*128 + ((kk*64 + g*16) ^ ((row & 7) << 4));
    return *(const bf16x8*)(sm + slot*65536 + 32768 + (wc >> 1)*16384 + b);
  };

  f32x4 acc[8][4] = {};

  stage(0, 0, 0, 0);
  stage(0, 0, 1, 0);
  stage(1, 0, 0, 0);
  stage(1, 0, 1, 0);
  stage(0, 1, 0, 1);
  asm volatile("s_waitcnt vmcnt(2)" ::: "memory");
  bar();

  const int niter = nkt_eff >> 1;
  for (int it = 0; it < niter; ++it) {
    const int t0 = 2*it, t1 = 2*it + 1;
    const int tn0 = (t0+2 < nkt_eff) ? t0+2 : nkt_eff-1;
    const int tn1 = (t1+2 < nkt_eff) ? t1+2 : nkt_eff-1;
    bf16x8 a0[4][2], a1[4][2], b0[2][2], b1[2][2];

    // P1
    #pragma unroll
    for (int m=0;m<4;++m) { a0[m][0]=aLoad(0,m,0); a0[m][1]=aLoad(0,m,1); }
    #pragma unroll
    for (int n=0;n<2;++n) { b0[n][0]=bLoad(0,n,0); b0[n][1]=bLoad(0,n,1); }
    stage(0, t1, 1, 1);
    bar();
    __builtin_amdgcn_s_setprio(1);
    #pragma unroll
    for (int m=0;m<4;++m)
      #pragma unroll
      for (int n=0;n<2;++n) {
        acc[m][n] = __builtin_amdgcn_mfma_f32_16x16x32_bf16(a0[m][0], b0[n][0], acc[m][n],0,0,0);
        acc[m][n] = __builtin_amdgcn_mfma_f32_16x16x32_bf16(a0[m][1], b0[n][1], acc[m][n],0,0,0);
      }
    __builtin_amdgcn_s_setprio(0);
    bar();
    // P2
    #pragma unroll
    for (int n=0;n<2;++n) { b1[n][0]=bLoad(0,n+2,0); b1[n][1]=bLoad(0,n+2,1); }
    stage(1, t1, 0, 1);
    bar();
    __builtin_amdgcn_s_setprio(1);
    #pragma unroll
    for (int m=0;m<4;++m)
      #pragma unroll
      for (int n=0;n<2;++n) {
        acc[m][n+2] = __builtin_amdgcn_mfma_f32_16x16x32_bf16(a0[m][0], b1[n][0], acc[m][n+2],0,0,0);
        acc[m][n+2] = __builtin_amdgcn_mfma_f32_16x16x32_bf16(a0[m][1], b1[n][1], acc[m][n+2],0,0,0);
      }
    __builtin_amdgcn_s_setprio(0);
    bar();
    // P3
    #pragma unroll
    for (int m=0;m<4;++m) { a1[m][0]=aLoad(0,m+4,0); a1[m][1]=aLoad(0,m+4,1); }
    stage(1, t1, 1, 1);
    bar();
    __builtin_amdgcn_s_setprio(1);
    #pragma unroll
    for (int m=0;m<4;++m)
      #pragma unroll
      for (int n=0;n<2;++n) {
        acc[m+4][n+2] = __builtin_amdgcn_mfma_f32_16x16x32_bf16(a1[m][0], b1[n][0], acc[m+4][n+2],0,0,0);
        acc[m+4][n+2] = __builtin_amdgcn_mfma_f32_16x16x32_bf16(a1[m][1], b1[n][1], acc[m+4][n+2],0,0,0);
      }
    __builtin_amdgcn_s_setprio(0);
    bar();
    // P4
    stage(0, tn0, 0, 0);
    asm volatile("s_waitcnt vmcnt(2)" ::: "memory");
    bar();
    __builtin_amdgcn_s_setprio(1);
    #pragma unroll
    for (int m=0;m<4;++m)
      #pragma unroll
      for (int n=0;n<2;++n) {
        acc[m+4][n] = __builtin_amdgcn_mfma_f32_16x16x32_bf16(a1[m][0], b0[n][0], acc[m+4][n],0,0,0);
        acc[m+4][n] = __builtin_amdgcn_mfma_f32_16x16x32_bf16(a1[m][1], b0[n][1], acc[m+4][n],0,0,0);
      }
    __builtin_amdgcn_s_setprio(0);
    bar();
    // P5
    #pragma unroll
    for (int m=0;m<4;++m) { a0[m][0]=aLoad(1,m,0); a0[m][1]=aLoad(1,m,1); }
    #pragma unroll
    for (int n=0;n<2;++n) { b0[n][0]=bLoad(1,n,0); b0[n][1]=bLoad(1,n,1); }
    stage(0, tn0, 1, 0);
    bar();
    __builtin_amdgcn_s_setprio(1);
    #pragma unroll
    for (int m=0;m<4;++m)
      #pragma unroll
      for (int n=0;n<2;++n) {
        acc[m][n] = __builtin_amdgcn_mfma_f32_16x16x32_bf16(a0[m][0], b0[n][0], acc[m][n],0,0,0);
        acc[m][n] = __builtin_amdgcn_mfma_f32_16x16x32_bf16(a0[m][1], b0[n][1], acc[m][n],0,0,0);
      }
    __builtin_amdgcn_s_setprio(0);
    bar();
    // P6
    #pragma unroll
    for (int n=0;n<2;++n) { b1[n][0]=bLoad(1,n+2,0); b1[n][1]=bLoad(1,n+2,1); }
    stage(1, tn0, 0, 0);
    bar();
    __builtin_amdgcn_s_setprio(1);
    #pragma unroll
    for (int m=0;m<4;++m)
      #pragma unroll
      for (int n=0;n<2;++n) {
        acc[m][n+2] = __builtin_amdgcn_mfma_f32_16x16x32_bf16(a0[m][0], b1[n][0], acc[m][n+2],0,0,0);
        acc[m][n+2] = __builtin_amdgcn_mfma_f32_16x16x32_bf16(a0[m][1], b1[n][1], acc[m][n+2],0,0,0);
      }
    __builtin_amdgcn_s_setprio(0);
    bar();
    // P7
    #pragma unroll
    for (int m=0;m<4;++m) { a1[m][0]=aLoad(1,m+4,0); a1[m][1]=aLoad(1,m+4,1); }
    stage(1, tn0, 1, 0);
    bar();
    __builtin_amdgcn_s_setprio(1);
    #pragma unroll
    for (int m=0;m<4;++m)
      #pragma unroll
      for (int n=0;n<2;++n) {
        acc[m+4][n+2] = __builtin_amdgcn_mfma_f32_16x16x32_bf16(a1[m][0], b1[n][0], acc[m+4][n+2],0,0,0);
        acc[m+4][n+2] = __builtin_amdgcn_mfma_f32_16x16x32_bf16(a1[m][1], b1[n][1], acc[m+4][n+2],0,0,0);
      }
    __builtin_amdgcn_s_setprio(0);
    bar();
    // P8
    stage(0, tn1, 0, 1);
    asm volatile("s_waitcnt vmcnt(2)" ::: "memory");
    bar();
    __builtin_amdgcn_s_setprio(1);
    #pragma unroll
    for (int m=0;m<4;++m)
      #pragma unroll
      for (int n=0;n<2;++n) {
        acc[m+4][n] = __builtin_amdgcn_mfma_f32_16x16x32_bf16(a1[m][0], b0[n][0], acc[m+4][n],0,0,0);
        acc[m+4][n] = __builtin_amdgcn_mfma_f32_16x16x32_bf16(a1[m][1], b0[n][1], acc[m+4][n],0,0,0);
      }
    __builtin_amdgcn_s_setprio(0);
    bar();
  }

  const long rowbase = (long)bm*256 + wr*128;
  const long colbase = (long)bn*256 + wc*64;

  #pragma unroll
  for (int m=0;m<8;++m)
    #pragma unroll
    for (int n=0;n<4;++n) {
      long c = colbase + n*16 + l15;
      #pragma unroll
      for (int q_=0;q_<4;++q_) {
        long rr = rowbase + m*16 + g*4 + q_;
        float v = acc[m][n][q_];
        if constexpr (EPI == EPI_F32) {
          outf[(long)bz*sOb + rr*ldo + c] = v;
        } else if constexpr (EPI == EPI_BF16) {
          outb[(long)bz*sOb + rr*ldo + c] = (bf16)v;
        } else if constexpr (EPI == EPI_BIAS_RELU_BF16) {
          outb[rr*ldo + c] = (bf16)fmaxf(v + bias[c], 0.f);
        } else if constexpr (EPI == EPI_BIAS_RES_BF16) {
          outb[rr*ldo + c] = (bf16)(v + bias[c] + res[rr*ldr + c]);
        } else if constexpr (EPI == EPI_RES_F32) {
          outf[(long)bz*sOb + rr*ldo + c] = v + res[(long)bz*sRb + rr*ldr + c];
        }
      }
    }
}

// ======== LM head: 128x128 tile, 256 thr, BK=64, double-buffered 2-phase ========
// T3 minimum-2-phase: stage(t+1, slot^1) issued BEFORE ds_read+MFMA of slot;
// vmcnt(0)+barrier only at loop bottom -> next-tile global latency hides under
// the 32-MFMA compute phase. LDS 64KB -> 2 blocks/CU. XOR swizzle s^(R&7),
// source pre-swizzled, read-side swizzled (rule 21), conflict-free ds_read_b128.
__global__ __launch_bounds__(256)
void lmhead128(const bf16* __restrict__ A, const bf16* __restrict__ B,
               const float* __restrict__ bias, float* __restrict__ outf,
               float* __restrict__ pmax, float* __restrict__ psum) {
  __shared__ char sm[65536];   // 2 slots x (A 16KB + B 16KB)
  const int bm = blockIdx.x, bn = blockIdx.y;   // bm fast
  const int tid = threadIdx.x;
  const int wid = tid >> 6, lane = tid & 63;
  const int wr = wid >> 1, wc = wid & 1;
  const int l15 = lane & 15, g = lane >> 4;

  // staging: thread t, load j in 0..3 per tensor: LDS position 256j+t (16B units),
  // LDS row R=(t>>3)+32j, slot t&7; source col pre-swizzled (t&7)^(R&7), R&7=(t>>3)&7
  const int rr_ = tid >> 3;
  const int colsw = 8 * ((tid & 7) ^ (rr_ & 7));
  const bf16* Abase = A + ((long)bm*128 + rr_)*NC + colsw;
  const bf16* Bbase = B + ((long)bn*128 + rr_)*NC + colsw;

  auto stage = [&](int kt, int slot) {
    char* dA = sm + slot*32768 + wid*1024;
    char* dB = sm + slot*32768 + 16384 + wid*1024;
    const bf16* a = Abase + kt*64;
    const bf16* b = Bbase + kt*64;
    #pragma unroll
    for (int j = 0; j < 4; ++j) {
      load_lds16(a + (long)j*32*NC, dA + j*4096);
      load_lds16(b + (long)j*32*NC, dB + j*4096);
    }
  };

  auto aLoad = [&](int slot, int m, int kk) -> bf16x8 {
    int R = wr*64 + m*16 + l15;
    int s = kk*4 + g;
    return *(const bf16x8*)(sm + slot*32768 + R*128 + ((s ^ (R & 7)) << 4));
  };
  auto bLoad = [&](int slot, int n, int kk) -> bf16x8 {
    int R = wc*64 + n*16 + l15;
    int s = kk*4 + g;
    return *(const bf16x8*)(sm + slot*32768 + 16384 + R*128 + ((s ^ (R & 7)) << 4));
  };

  f32x4 acc[4][4] = {};

  stage(0, 0);
  asm volatile("s_waitcnt vmcnt(0)" ::: "memory");
  bar();

  int cur = 0;
  for (int kt = 0; kt < 8; ++kt) {
    if (kt < 7) stage(kt + 1, cur ^ 1);   // in flight across the MFMA phase
    bf16x8 af[4][2], bf_[4][2];
    #pragma unroll
    for (int m=0;m<4;++m) { af[m][0]=aLoad(cur,m,0); af[m][1]=aLoad(cur,m,1); }
    #pragma unroll
    for (int n=0;n<4;++n) { bf_[n][0]=bLoad(cur,n,0); bf_[n][1]=bLoad(cur,n,1); }
    __builtin_amdgcn_s_setprio(1);
    #pragma unroll
    for (int m=0;m<4;++m)
      #pragma unroll
      for (int n=0;n<4;++n) {
        acc[m][n] = __builtin_amdgcn_mfma_f32_16x16x32_bf16(af[m][0], bf_[n][0], acc[m][n],0,0,0);
        acc[m][n] = __builtin_amdgcn_mfma_f32_16x16x32_bf16(af[m][1], bf_[n][1], acc[m][n],0,0,0);
      }
    __builtin_amdgcn_s_setprio(0);
    asm volatile("s_waitcnt vmcnt(0)" ::: "memory");   // next tile resident
    bar();                                             // all waves done with cur
    cur ^= 1;
  }

  const long rowb = (long)bm*128;
  const long colb = (long)bn*128;
  #pragma unroll
  for (int m=0;m<4;++m)
    #pragma unroll
    for (int n=0;n<4;++n) {
      long c = colb + wc*64 + n*16 + l15;
      float bv = bias[c];
      #pragma unroll
      for (int q=0;q<4;++q) {
        acc[m][n][q] += bv;
        long rr = rowb + wr*64 + m*16 + g*4 + q;
        __builtin_nontemporal_store(acc[m][n][q], &outf[rr*NV + c]);
      }
    }
  __syncthreads();
  float* redm = (float*)sm;          // [2][128]
  float* reds = redm + 256;
  #pragma unroll
  for (int m=0;m<4;++m)
    #pragma unroll
    for (int q=0;q<4;++q) {
      float mx = fmaxf(fmaxf(acc[m][0][q], acc[m][1][q]),
                       fmaxf(acc[m][2][q], acc[m][3][q]));
      #pragma unroll
      for (int msk=8;msk>=1;msk>>=1) mx = fmaxf(mx, __shfl_xor(mx, msk));
      float se = 0.f;
      #pragma unroll
      for (int n=0;n<4;++n) se += __expf(acc[m][n][q] - mx);
      #pragma unroll
      for (int msk=8;msk>=1;msk>>=1) se += __shfl_xor(se, msk);
      if (l15 == 0) {
        int R = wr*64 + m*16 + g*4 + q;
        redm[wc*128 + R] = mx;
        reds[wc*128 + R] = se;
      }
    }
  __syncthreads();
  if (tid < 128) {
    float m0 = redm[tid], m1 = redm[128+tid];
    float M = fmaxf(m0, m1);
    float Sv = reds[tid]*__expf(m0-M) + reds[128+tid]*__expf(m1-M);
    long row = rowb + tid;
    pmax[row*NCHUNK + bn] = M;
    psum[row*NCHUNK + bn] = Sv;
  }
}

// ---------------- PV combine + LN2: x1 = x0 + sum_c part[c]; h2 = LN(x1) ------
__global__ __launch_bounds__(64)
void pv_combine_ln_kernel(const float* __restrict__ part, const float* __restrict__ x0,
                          const float* __restrict__ gw, const float* __restrict__ bw,
                          float* __restrict__ x1, bf16* __restrict__ h2) {
  int row = blockIdx.x;
  int b = row >> 11, t = row & (NT-1);
  int lane = threadIdx.x;
  int nC = (t >> 9) + 1;
  const float* xr = x0 + (long)row*NC + lane*8;
  f32x4 a0 = *(const f32x4*)xr, a1 = *(const f32x4*)(xr+4);
  for (int c = 0; c < nC; ++c) {
    const float* pr = part + ((long)(c*4 + b)*NT + t)*NC + lane*8;
    a0 += *(const f32x4*)pr; a1 += *(const f32x4*)(pr+4);
  }
  float* o = x1 + (long)row*NC + lane*8;
  *(f32x4*)o = a0; *(f32x4*)(o+4) = a1;
  float v[8] = {a0.x,a0.y,a0.z,a0.w,a1.x,a1.y,a1.z,a1.w};
  float s = 0.f;
  #pragma unroll
  for (int j=0;j<8;++j) s += v[j];
  #pragma unroll
  for (int m=32;m>=1;m>>=1) s += __shfl_xor(s, m);
  float mu = s * (1.f/NC);
  float sq = 0.f;
  #pragma unroll
  for (int j=0;j<8;++j) { v[j] -= mu; sq += v[j]*v[j]; }
  #pragma unroll
  for (int m=32;m>=1;m>>=1) sq += __shfl_xor(sq, m);
  float rs = rsqrtf(sq * (1.f/NC) + LNEPS);
  const float* gp = gw + lane*8;
  const float* bp = bw + lane*8;
  f32x4 g0 = *(const f32x4*)gp, g1 = *(const f32x4*)(gp+4);
  f32x4 b0 = *(const f32x4*)bp, b1 = *(const f32x4*)(bp+4);
  float gg[8] = {g0.x,g0.y,g0.z,g0.w,g1.x,g1.y,g1.z,g1.w};
  float bb[8] = {b0.x,b0.y,b0.z,b0.w,b1.x,b1.y,b1.z,b1.w};
  bf16x8 oo;
  #pragma unroll
  for (int j=0;j<8;++j) oo[j] = (bf16)(v[j]*rs*gg[j] + bb[j]);
  *(bf16x8*)(h2 + (long)row*NC + lane*8) = oo;
}

// ---------------- FFN2 combine: x2 = bf16(x1 + b2 + sum_z part2[z]) ----------
__global__ __launch_bounds__(64)
void ffn2_combine_kernel(const float* __restrict__ part, const float* __restrict__ x1,
                         const float* __restrict__ b2, bf16* __restrict__ x2) {
  int row = blockIdx.x;
  int lane = threadIdx.x;
  const float* xr = x1 + (long)row*NC + lane*8;
  f32x4 a0 = *(const f32x4*)xr, a1 = *(const f32x4*)(xr+4);
  const float* br = b2 + lane*8;
  a0 += *(const f32x4*)br; a1 += *(const f32x4*)(br+4);
  #pragma unroll
  for (int z = 0; z < 4; ++z) {
    const float* pr = part + ((long)z*NROWS + row)*NC + lane*8;
    a0 += *(const f32x4*)pr; a1 += *(const f32x4*)(pr+4);
  }
  bf16x8 o;
  o[0]=(bf16)a0.x; o[1]=(bf16)a0.y; o[2]=(bf16)a0.z; o[3]=(bf16)a0.w;
  o[4]=(bf16)a1.x; o[5]=(bf16)a1.y; o[6]=(bf16)a1.z; o[7]=(bf16)a1.w;
  *(bf16x8*)(x2 + (long)row*NC + lane*8) = o;
}

// ---------------- loss pass 1 ----------------
__global__ __launch_bounds__(256)
void loss1_kernel(const float* __restrict__ pmax, const float* __restrict__ psum,
                  const float* __restrict__ logits, const int* __restrict__ targets,
                  float* __restrict__ rowloss) {
  int row = blockIdx.x;
  int tid = threadIdx.x;
  int lane = tid & 63, wv = tid >> 6;
  float cm = (tid < NCHUNK) ? pmax[(long)row*NCHUNK + tid] : -1e30f;
  float cs = (tid < NCHUNK) ? psum[(long)row*NCHUNK + tid] : 0.f;
  float mx = cm;
  #pragma unroll
  for (int m=32;m>=1;m>>=1) mx = fmaxf(mx, __shfl_xor(mx, m));
  __shared__ float rm[4];
  if (lane == 0) rm[wv] = mx;
  __syncthreads();
  float M = fmaxf(fmaxf(rm[0],rm[1]), fmaxf(rm[2],rm[3]));
  float sc = cs * __expf(cm - M);
  #pragma unroll
  for (int m=32;m>=1;m>>=1) sc += __shfl_xor(sc, m);
  __shared__ float rs_[4];
  if (lane == 0) rs_[wv] = sc;
  __syncthreads();
  if (tid == 0) {
    float Sv = rs_[0]+rs_[1]+rs_[2]+rs_[3];
    float lse = M + logf(Sv);
    int tgt = targets[row];
    float lg = logits[(long)row*NV + tgt];
    rowloss[row] = lse - lg;
  }
}

// ---------------- loss pass 2 ----------------
__global__ __launch_bounds__(256)
void loss2_kernel(const float* __restrict__ rowloss, float* __restrict__ out) {
  int tid = threadIdx.x;
  float s = 0.f;
  for (int i = tid; i < NROWS; i += 256) s += rowloss[i];
  #pragma unroll
  for (int m=32;m>=1;m>>=1) s += __shfl_xor(s, m);
  __shared__ float rs_[4];
  if ((tid & 63) == 0) rs_[tid>>6] = s;
  __syncthreads();
  if (tid == 0) out[0] = (rs_[0]+rs_[1]+rs_[2]+rs_[3]) * (1.f/NROWS);
}

// ---------------- launcher ----------------
extern "C" void kernel_launch(void* const* d_in, const int* in_sizes, int n_in,
                              void* d_out, int out_size, void* d_ws, size_t ws_size,
                              hipStream_t stream) {
  const int*   idx  = (const int*)d_in[0];
  const int*   tgt  = (const int*)d_in[1];
  const float* tok  = (const float*)d_in[2];
  const float* pos  = (const float*)d_in[3];
  const float* Wk   = (const float*)d_in[4];
  const float* Wq   = (const float*)d_in[5];
  const float* Wv   = (const float*)d_in[6];
  const float* W1   = (const float*)d_in[7];
  const float* b1   = (const float*)d_in[8];
  const float* W2   = (const float*)d_in[9];
  const float* b2   = (const float*)d_in[10];
  const float* g1   = (const float*)d_in[11];
  const float* be1  = (const float*)d_in[12];
  const float* g2   = (const float*)d_in[13];
  const float* be2  = (const float*)d_in[14];
  const float* Wlm  = (const float*)d_in[15];
  const float* blm  = (const float*)d_in[16];

  float* logits = (float*)d_out;
  float* loss   = logits + (long)NROWS*NV;

  char* w = (char*)d_ws;
  auto alloc = [&](size_t bytes) -> char* {
    char* p = w; w += (bytes + 255) & ~(size_t)255; return p;
  };
  bf16* wqkvb = (bf16*)alloc((size_t)3*NC*NC*2);
  bf16* w1b   = (bf16*)alloc((size_t)4*NC*NC*2);
  bf16* w2b   = (bf16*)alloc((size_t)4*NC*NC*2);
  bf16* wlmb  = (bf16*)alloc((size_t)NV*NC*2);
  float* x0   = (float*)alloc((size_t)NROWS*NC*4);
  bf16* h1b   = (bf16*)alloc((size_t)NROWS*NC*2);
  bf16* qkvb  = (bf16*)alloc((size_t)NROWS*3*NC*2);
  bf16* vtb   = (bf16*)alloc((size_t)NROWS*NC*2);
  float* Sb   = (float*)alloc((size_t)NB*NT*NT*4);      // P bf16 aliased; FFN2 partials alias
  float* pvp  = (float*)alloc((size_t)16*NT*NC*4);      // PV split-K partials
  float* x1   = (float*)alloc((size_t)NROWS*NC*4);
  bf16* h2b   = (bf16*)alloc((size_t)NROWS*NC*2);
  bf16* ffb   = (bf16*)alloc((size_t)NROWS*4*NC*2);
  bf16* x2b   = (bf16*)alloc((size_t)NROWS*NC*2);
  float* pmax = (float*)alloc((size_t)NROWS*NCHUNK*4);
  float* psum = (float*)alloc((size_t)NROWS*NCHUNK*4);
  float* rowloss = (float*)alloc((size_t)NROWS*4);
  float* ff2p = Sb;   // [4][8192][512] f32, aliases Sb (P dead by FFN2)

  hipFuncSetAttribute((const void*)gemm256<EPI_BF16,false,false,false>,
                      hipFuncAttributeMaxDynamicSharedMemorySize, SMEM_B);
  hipFuncSetAttribute((const void*)gemm256<EPI_F32,true,false,false>,
                      hipFuncAttributeMaxDynamicSharedMemorySize, SMEM_B);
  hipFuncSetAttribute((const void*)gemm256<EPI_F32,false,false,true>,
                      hipFuncAttributeMaxDynamicSharedMemorySize, SMEM_B);
  hipFuncSetAttribute((const void*)gemm256<EPI_F32,false,false,false>,
                      hipFuncAttributeMaxDynamicSharedMemorySize, SMEM_B);
  hipFuncSetAttribute((const void*)gemm256<EPI_BIAS_RELU_BF16,false,true,false>,
                      hipFuncAttributeMaxDynamicSharedMemorySize, SMEM_B);

  auto cvt = [&](const float* in, bf16* out, long n) {
    int n8 = (int)(n/8);
    int blocks = (n8 + 255)/256; if (blocks > 2048) blocks = 2048;
    cvt_kernel<<<blocks, 256, 0, stream>>>(in, out, n8);
  };
  cvt(Wq, wqkvb, (long)NC*NC);
  cvt(Wk, wqkvb + (long)NC*NC, (long)NC*NC);
  cvt(Wv, wqkvb + (long)2*NC*NC, (long)NC*NC);
  cvt(W1, w1b, (long)4*NC*NC);
  cvt(W2, w2b, (long)4*NC*NC);
  cvt(Wlm, wlmb, (long)NV*NC);

  embed_ln_kernel<<<NROWS, 64, 0, stream>>>(idx, tok, pos, g1, be1, x0, h1b);

  // fused QKV
  gemm256<EPI_BF16><<<dim3(6,32,1), 512, SMEM_B, stream>>>(
      h1b, wqkvb, 8, NC, NC, 0, 0, nullptr, qkvb, 3*NC, 0,
      nullptr, nullptr, 0, 0);

  transpose_kernel<<<dim3(NT/64, NC/64, NB), 256, 0, stream>>>(qkvb + 2*NC, 3*NC, vtb);

  // S = q k^T (per batch), causal block skip
  gemm256<EPI_F32,true><<<dim3(8,8,NB), 512, SMEM_B, stream>>>(
      qkvb, qkvb + NC, 8, 3*NC, 3*NC, (long)NT*3*NC, (long)NT*3*NC,
      Sb, nullptr, NT, (long)NT*NT,
      nullptr, nullptr, 0, 0);

  softmax_kernel<<<NROWS, 256, 0, stream>>>(Sb);

  // PV split-K over kv chunks: z = c*4 + b; partials -> pvp[z]
  gemm256<EPI_F32,false,false,true><<<dim3(2,8,16), 512, SMEM_B, stream>>>(
      (const bf16*)Sb, vtb, 8, 2*NT, NT, (long)NT*2*NT, (long)NC*NT,
      pvp, nullptr, NC, (long)NT*NC,
      nullptr, nullptr, 0, 0);

  // x1 = x0 + sum_c pvp; h2 = LN2(x1)
  pv_combine_ln_kernel<<<NROWS, 64, 0, stream>>>(pvp, x0, g2, be2, x1, h2b);

  // ff = relu(h2 W1^T + b1)
  gemm256<EPI_BIAS_RELU_BF16,false,true><<<dim3(32,8,1), 512, SMEM_B, stream>>>(
      h2b, w1b, 8, NC, NC, 0, 0, nullptr, ffb, 4*NC, 0,
      b1, nullptr, 0, 0);

  // FFN2 split-K x4
  gemm256<EPI_F32><<<dim3(2,32,4), 512, SMEM_B, stream>>>(
      ffb, w2b, 8, 4*NC, 4*NC, 512, 512,
      ff2p, nullptr, NC, (long)NROWS*NC,
      nullptr, nullptr, 0, 0);

  ffn2_combine_kernel<<<NROWS, 64, 0, stream>>>(ff2p, x1, b2, x2b);

  // LM head: double-buffered 2-phase 128^2, 2 blocks/CU, fused epilogue
  lmhead128<<<dim3(64, NCHUNK), 256, 0, stream>>>(x2b, wlmb, blm, logits, pmax, psum);

  loss1_kernel<<<NROWS, 256, 0, stream>>>(pmax, psum, logits, tgt, rowloss);
  loss2_kernel<<<1, 256, 0, stream>>>(rowloss, loss);
}

// Round 10
// 742.517 us; speedup vs baseline: 1.0903x; 1.0903x over previous
//
#include <hip/hip_runtime.h>

typedef __bf16 bf16;
typedef __bf16 bf16x8 __attribute__((ext_vector_type(8)));
typedef float  f32x4  __attribute__((ext_vector_type(4)));

#define NB 4
#define NT 2048
#define NC 512
#define NV 32000
#define NROWS (NB*NT)          // 8192
#define NCHUNK 500             // 64-col chunks for LM-head partials
#define LNEPS 1e-5f
#define SMEM_B 131072

static __device__ __forceinline__ void load_lds16(const bf16* g, char* l) {
  __builtin_amdgcn_global_load_lds(
      (const __attribute__((address_space(1))) void*)g,
      (__attribute__((address_space(3))) void*)l, 16, 0, 0);
}

static __device__ __forceinline__ void bar() {
  asm volatile("" ::: "memory");
  __builtin_amdgcn_s_barrier();
  asm volatile("" ::: "memory");
}

// ---------------- f32 -> bf16 convert ----------------
__global__ __launch_bounds__(256)
void cvt_kernel(const float* __restrict__ in, bf16* __restrict__ out, int n8) {
  long i = (long)blockIdx.x * 256 + threadIdx.x;
  long stride = (long)gridDim.x * 256;
  for (; i < n8; i += stride) {
    const float* p = in + i * 8;
    f32x4 a = *(const f32x4*)p;
    f32x4 b = *(const f32x4*)(p + 4);
    bf16x8 o;
    o[0]=(bf16)a.x; o[1]=(bf16)a.y; o[2]=(bf16)a.z; o[3]=(bf16)a.w;
    o[4]=(bf16)b.x; o[5]=(bf16)b.y; o[6]=(bf16)b.z; o[7]=(bf16)b.w;
    *(bf16x8*)(out + i*8) = o;
  }
}

// ---------------- fused embedding + layernorm1 ----------------
__global__ __launch_bounds__(64)
void embed_ln_kernel(const int* __restrict__ idx, const float* __restrict__ tok,
                     const float* __restrict__ pos, const float* __restrict__ gw,
                     const float* __restrict__ bw,
                     float* __restrict__ x0, bf16* __restrict__ h1) {
  int row = blockIdx.x;
  int t = row & (NT-1);
  int id = idx[row];
  int lane = threadIdx.x;
  const float* tr = tok + (long)id*NC + lane*8;
  const float* pr = pos + (long)t*NC + lane*8;
  f32x4 a0 = *(const f32x4*)tr, a1 = *(const f32x4*)(tr+4);
  f32x4 p0 = *(const f32x4*)pr, p1 = *(const f32x4*)(pr+4);
  f32x4 r0 = a0 + p0, r1 = a1 + p1;
  float* o = x0 + (long)row*NC + lane*8;
  *(f32x4*)o = r0; *(f32x4*)(o+4) = r1;
  float v[8] = {r0.x,r0.y,r0.z,r0.w,r1.x,r1.y,r1.z,r1.w};
  float s = 0.f;
  #pragma unroll
  for (int j=0;j<8;++j) s += v[j];
  #pragma unroll
  for (int m=32;m>=1;m>>=1) s += __shfl_xor(s, m);
  float mu = s * (1.f/NC);
  float sq = 0.f;
  #pragma unroll
  for (int j=0;j<8;++j) { v[j] -= mu; sq += v[j]*v[j]; }
  #pragma unroll
  for (int m=32;m>=1;m>>=1) sq += __shfl_xor(sq, m);
  float rs = rsqrtf(sq * (1.f/NC) + LNEPS);
  const float* gp = gw + lane*8;
  const float* bp = bw + lane*8;
  f32x4 g0 = *(const f32x4*)gp, g1 = *(const f32x4*)(gp+4);
  f32x4 b0 = *(const f32x4*)bp, b1 = *(const f32x4*)(bp+4);
  float gg[8] = {g0.x,g0.y,g0.z,g0.w,g1.x,g1.y,g1.z,g1.w};
  float bb[8] = {b0.x,b0.y,b0.z,b0.w,b1.x,b1.y,b1.z,b1.w};
  bf16x8 oo;
  #pragma unroll
  for (int j=0;j<8;++j) oo[j] = (bf16)(v[j]*rs*gg[j] + bb[j]);
  *(bf16x8*)(h1 + (long)row*NC + lane*8) = oo;
}

// ---------------- transpose v[b][t][c] (stride ldv) -> vt[b][c][t] ----------------
__global__ __launch_bounds__(256)
void transpose_kernel(const bf16* __restrict__ v, long ldv, bf16* __restrict__ vt) {
  __shared__ bf16 tile[64][66];
  int b = blockIdx.z;
  int t0 = blockIdx.x*64, c0 = blockIdx.y*64;
  int tid = threadIdx.x;
  int r = tid >> 2, ch = (tid & 3) * 16;
  const bf16* src = v + ((long)b*NT + t0 + r)*ldv + c0 + ch;
  #pragma unroll
  for (int i=0;i<16;++i) tile[r][ch+i] = src[i];
  __syncthreads();
  bf16x8 o0, o1;
  #pragma unroll
  for (int i=0;i<8;++i) o0[i] = tile[ch+i][r];
  #pragma unroll
  for (int i=0;i<8;++i) o1[i] = tile[ch+8+i][r];
  bf16* dst = vt + ((long)b*NC + c0 + r)*NT + t0 + ch;
  *(bf16x8*)dst = o0;
  *(bf16x8*)(dst+8) = o1;
}

// ---------------- causal softmax row: S f32 -> P bf16 (aliased into S) ----------------
__global__ __launch_bounds__(256)
void softmax_kernel(float* __restrict__ S) {
  const int row = blockIdx.x;
  const int t = row & (NT-1);
  const int tid = threadIdx.x;
  float* sr = S + (long)row*NT;
  bf16* pr = (bf16*)S + (long)row*(2*NT);
  const float scale = 0.044194173824159216f;
  f32x4 v0 = *(const f32x4*)(sr + tid*8);
  f32x4 v1 = *(const f32x4*)(sr + tid*8 + 4);
  float v[8] = {v0.x,v0.y,v0.z,v0.w,v1.x,v1.y,v1.z,v1.w};
  int cb = tid*8;
  float mx = -1e30f;
  #pragma unroll
  for (int j=0;j<8;++j) {
    v[j] = (cb + j <= t) ? v[j]*scale : -1e30f;
    mx = fmaxf(mx, v[j]);
  }
  __shared__ float redm[4];
  #pragma unroll
  for (int m=32;m>=1;m>>=1) mx = fmaxf(mx, __shfl_xor(mx, m));
  if ((tid & 63) == 0) redm[tid>>6] = mx;
  __syncthreads();
  mx = fmaxf(fmaxf(redm[0],redm[1]), fmaxf(redm[2],redm[3]));
  float e[8]; float s = 0.f;
  #pragma unroll
  for (int j=0;j<8;++j) { e[j] = (cb + j <= t) ? __expf(v[j]-mx) : 0.f; s += e[j]; }
  __shared__ float reds[4];
  #pragma unroll
  for (int m=32;m>=1;m>>=1) s += __shfl_xor(s, m);
  if ((tid & 63) == 0) reds[tid>>6] = s;
  __syncthreads();
  s = reds[0]+reds[1]+reds[2]+reds[3];
  float inv = 1.f/s;
  bf16x8 o;
  #pragma unroll
  for (int j=0;j<8;++j) o[j] = (bf16)(e[j]*inv);
  *(bf16x8*)(pr + cb) = o;
}

// ======== 256x256-tile 8-phase GEMM: out[M,N] = A[M,K] * B[N,K]^T ========
enum { EPI_F32=0, EPI_BF16=1, EPI_BIAS_RELU_BF16=2, EPI_BIAS_RES_BF16=3, EPI_RES_F32=4 };

template<int EPI, bool CAUSAL=false, bool SWAP=false, bool KCHUNK=false>
__global__ __launch_bounds__(512,2)
void gemm256(const bf16* __restrict__ A, const bf16* __restrict__ B, int nkt,
             long lda, long ldb, long sAb, long sBb,
             float* __restrict__ outf, bf16* __restrict__ outb, long ldo, long sOb,
             const float* __restrict__ bias,
             const float* __restrict__ res, long ldr, long sRb) {
  extern __shared__ char smem[];
  int bn, bm;
  if constexpr (SWAP) { bm = blockIdx.x; bn = blockIdx.y; }
  else               { bn = blockIdx.x; bm = blockIdx.y; }
  const int bz = blockIdx.z;
  if constexpr (CAUSAL) { if (bn > bm) return; }
  int nkt_eff = nkt;
  int bzAB = bz;
  long kOff = 0;
  if constexpr (KCHUNK) {
    int c = bz >> 2; bzAB = bz & 3;
    int lim = (bm+1)*4 - c*8;
    if (lim <= 0) return;
    if (lim < nkt_eff) nkt_eff = lim;
    kOff = (long)c*512;
  }

  const int tid = threadIdx.x;
  const int wid = tid >> 6, lane = tid & 63;
  const int wr = wid >> 2, wc = wid & 3;
  const int l15 = lane & 15, g = lane >> 4;

  const bf16* Ab = A + (long)bzAB*sAb + kOff + (long)bm*256*lda;
  const bf16* Bb = B + (long)bzAB*sBb + kOff + (long)bn*256*ldb;

  const int colsw = 8 * ((tid & 7) ^ ((tid >> 3) & 7));
  const bf16* A0 = Ab + (long)(tid >> 3)*lda + colsw;
  const bf16* B0 = Bb + (long)(tid >> 3)*ldb + colsw;

  auto stage = [&](int ab, int t, int h, int slot) {
    char* dst = smem + slot*65536 + ab*32768 + h*16384 + wid*1024;
    const bf16* s0 = (ab ? B0 : A0) + (long)(h*128)*(ab ? ldb : lda) + (long)t*64;
    load_lds16(s0, dst);
    load_lds16(s0 + 64*(ab ? ldb : lda), dst + 8192);
  };

  const char* sm = smem;
  auto aLoad = [&](int slot, int m, int kk) -> bf16x8 {
    int row = m*16 + l15;
    int b = row*128 + ((kk*64 + g*16) ^ ((row & 7) << 4));
    return *(const bf16x8*)(sm + slot*65536 + wr*16384 + b);
  };
  auto bLoad = [&](int slot, int n, int kk) -> bf16x8 {
    int row = (wc & 1)*64 + n*16 + l15;
    int b = row*128 + ((kk*64 + g*16) ^ ((row & 7) << 4));
    return *(const bf16x8*)(sm + slot*65536 + 32768 + (wc >> 1)*16384 + b);
  };

  f32x4 acc[8][4] = {};

  stage(0, 0, 0, 0);
  stage(0, 0, 1, 0);
  stage(1, 0, 0, 0);
  stage(1, 0, 1, 0);
  stage(0, 1, 0, 1);
  asm volatile("s_waitcnt vmcnt(2)" ::: "memory");
  bar();

  const int niter = nkt_eff >> 1;
  for (int it = 0; it < niter; ++it) {
    const int t0 = 2*it, t1 = 2*it + 1;
    const int tn0 = (t0+2 < nkt_eff) ? t0+2 : nkt_eff-1;
    const int tn1 = (t1+2 < nkt_eff) ? t1+2 : nkt_eff-1;
    bf16x8 a0[4][2], a1[4][2], b0[2][2], b1[2][2];

    // P1
    #pragma unroll
    for (int m=0;m<4;++m) { a0[m][0]=aLoad(0,m,0); a0[m][1]=aLoad(0,m,1); }
    #pragma unroll
    for (int n=0;n<2;++n) { b0[n][0]=bLoad(0,n,0); b0[n][1]=bLoad(0,n,1); }
    stage(0, t1, 1, 1);
    bar();
    __builtin_amdgcn_s_setprio(1);
    #pragma unroll
    for (int m=0;m<4;++m)
      #pragma unroll
      for (int n=0;n<2;++n) {
        acc[m][n] = __builtin_amdgcn_mfma_f32_16x16x32_bf16(a0[m][0], b0[n][0], acc[m][n],0,0,0);
        acc[m][n] = __builtin_amdgcn_mfma_f32_16x16x32_bf16(a0[m][1], b0[n][1], acc[m][n],0,0,0);
      }
    __builtin_amdgcn_s_setprio(0);
    bar();
    // P2
    #pragma unroll
    for (int n=0;n<2;++n) { b1[n][0]=bLoad(0,n+2,0); b1[n][1]=bLoad(0,n+2,1); }
    stage(1, t1, 0, 1);
    bar();
    __builtin_amdgcn_s_setprio(1);
    #pragma unroll
    for (int m=0;m<4;++m)
      #pragma unroll
      for (int n=0;n<2;++n) {
        acc[m][n+2] = __builtin_amdgcn_mfma_f32_16x16x32_bf16(a0[m][0], b1[n][0], acc[m][n+2],0,0,0);
        acc[m][n+2] = __builtin_amdgcn_mfma_f32_16x16x32_bf16(a0[m][1], b1[n][1], acc[m][n+2],0,0,0);
      }
    __builtin_amdgcn_s_setprio(0);
    bar();
    // P3
    #pragma unroll
    for (int m=0;m<4;++m) { a1[m][0]=aLoad(0,m+4,0); a1[m][1]=aLoad(0,m+4,1); }
    stage(1, t1, 1, 1);
    bar();
    __builtin_amdgcn_s_setprio(1);
    #pragma unroll
    for (int m=0;m<4;++m)
      #pragma unroll
      for (int n=0;n<2;++n) {
        acc[m+4][n+2] = __builtin_amdgcn_mfma_f32_16x16x32_bf16(a1[m][0], b1[n][0], acc[m+4][n+2],0,0,0);
        acc[m+4][n+2] = __builtin_amdgcn_mfma_f32_16x16x32_bf16(a1[m][1], b1[n][1], acc[m+4][n+2],0,0,0);
      }
    __builtin_amdgcn_s_setprio(0);
    bar();
    // P4
    stage(0, tn0, 0, 0);
    asm volatile("s_waitcnt vmcnt(2)" ::: "memory");
    bar();
    __builtin_amdgcn_s_setprio(1);
    #pragma unroll
    for (int m=0;m<4;++m)
      #pragma unroll
      for (int n=0;n<2;++n) {
        acc[m+4][n] = __builtin_amdgcn_mfma_f32_16x16x32_bf16(a1[m][0], b0[n][0], acc[m+4][n],0,0,0);
        acc[m+4][n] = __builtin_amdgcn_mfma_f32_16x16x32_bf16(a1[m][1], b0[n][1], acc[m+4][n],0,0,0);
      }
    __builtin_amdgcn_s_setprio(0);
    bar();
    // P5
    #pragma unroll
    for (int m=0;m<4;++m) { a0[m][0]=aLoad(1,m,0); a0[m][1]=aLoad(1,m,1); }
    #pragma unroll
    for (int n=0;n<2;++n) { b0[n][0]=bLoad(1,n,0); b0[n][1]=bLoad(1,n,1); }
    stage(0, tn0, 1, 0);
    bar();
    __builtin_amdgcn_s_setprio(1);
    #pragma unroll
    for (int m=0;m<4;++m)
      #pragma unroll
      for (int n=0;n<2;++n) {
        acc[m][n] = __builtin_amdgcn_mfma_f32_16x16x32_bf16(a0[m][0], b0[n][0], acc[m][n],0,0,0);
        acc[m][n] = __builtin_amdgcn_mfma_f32_16x16x32_bf16(a0[m][1], b0[n][1], acc[m][n],0,0,0);
      }
    __builtin_amdgcn_s_setprio(0);
    bar();
    // P6
    #pragma unroll
    for (int n=0;n<2;++n) { b1[n][0]=bLoad(1,n+2,0); b1[n][1]=bLoad(1,n+2,1); }
    stage(1, tn0, 0, 0);
    bar();
    __builtin_amdgcn_s_setprio(1);
    #pragma unroll
    for (int m=0;m<4;++m)
      #pragma unroll
      for (int n=0;n<2;++n) {
        acc[m][n+2] = __builtin_amdgcn_mfma_f32_16x16x32_bf16(a0[m][0], b1[n][0], acc[m][n+2],0,0,0);
        acc[m][n+2] = __builtin_amdgcn_mfma_f32_16x16x32_bf16(a0[m][1], b1[n][1], acc[m][n+2],0,0,0);
      }
    __builtin_amdgcn_s_setprio(0);
    bar();
    // P7
    #pragma unroll
    for (int m=0;m<4;++m) { a1[m][0]=aLoad(1,m+4,0); a1[m][1]=aLoad(1,m+4,1); }
    stage(1, tn0, 1, 0);
    bar();
    __builtin_amdgcn_s_setprio(1);
    #pragma unroll
    for (int m=0;m<4;++m)
      #pragma unroll
      for (int n=0;n<2;++n) {
        acc[m+4][n+2] = __builtin_amdgcn_mfma_f32_16x16x32_bf16(a1[m][0], b1[n][0], acc[m+4][n+2],0,0,0);
        acc[m+4][n+2] = __builtin_amdgcn_mfma_f32_16x16x32_bf16(a1[m][1], b1[n][1], acc[m+4][n+2],0,0,0);
      }
    __builtin_amdgcn_s_setprio(0);
    bar();
    // P8
    stage(0, tn1, 0, 1);
    asm volatile("s_waitcnt vmcnt(2)" ::: "memory");
    bar();
    __builtin_amdgcn_s_setprio(1);
    #pragma unroll
    for (int m=0;m<4;++m)
      #pragma unroll
      for (int n=0;n<2;++n) {
        acc[m+4][n] = __builtin_amdgcn_mfma_f32_16x16x32_bf16(a1[m][0], b0[n][0], acc[m+4][n],0,0,0);
        acc[m+4][n] = __builtin_amdgcn_mfma_f32_16x16x32_bf16(a1[m][1], b0[n][1], acc[m+4][n],0,0,0);
      }
    __builtin_amdgcn_s_setprio(0);
    bar();
  }

  const long rowbase = (long)bm*256 + wr*128;
  const long colbase = (long)bn*256 + wc*64;

  #pragma unroll
  for (int m=0;m<8;++m)
    #pragma unroll
    for (int n=0;n<4;++n) {
      long c = colbase + n*16 + l15;
      #pragma unroll
      for (int q_=0;q_<4;++q_) {
        long rr = rowbase + m*16 + g*4 + q_;
        float v = acc[m][n][q_];
        if constexpr (EPI == EPI_F32) {
          outf[(long)bz*sOb + rr*ldo + c] = v;
        } else if constexpr (EPI == EPI_BF16) {
          outb[(long)bz*sOb + rr*ldo + c] = (bf16)v;
        } else if constexpr (EPI == EPI_BIAS_RELU_BF16) {
          outb[rr*ldo + c] = (bf16)fmaxf(v + bias[c], 0.f);
        } else if constexpr (EPI == EPI_BIAS_RES_BF16) {
          outb[rr*ldo + c] = (bf16)(v + bias[c] + res[rr*ldr + c]);
        } else if constexpr (EPI == EPI_RES_F32) {
          outf[(long)bz*sOb + rr*ldo + c] = v + res[(long)bz*sRb + rr*ldr + c];
        }
      }
    }
}

// ======== LM head: 128x128 tile, BK=32, double-buffered in 32KB LDS ========
// 4 blocks/CU (launch_bounds(256,4)) -> cross-block latency hiding (m114)
// PLUS intra-block prefetch (stage(kt+1) before compute, vmcnt(0) at bottom).
// Barrier-FREE epilogue: per-wave 64-col softmax partials via shfl only;
// logits stores fire-and-forget (wave retires while stores drain).
// LDS pack-swizzle (R8-verified): lds row 128B = two 64B tile rows; 16B slot
// s holds global K-slot s^((R>>1)&3) -> 2-way bank aliasing (free).
__global__ __launch_bounds__(256,4)
void lmhead128(const bf16* __restrict__ A, const bf16* __restrict__ B,
               const float* __restrict__ bias, float* __restrict__ outf,
               float* __restrict__ pmax, float* __restrict__ psum) {
  __shared__ char sm[32768];   // 2 slots x (A 8KB + B 8KB)
  const int bm = blockIdx.x, bn = blockIdx.y;   // bm fast: panel shared by 64 blocks
  const int tid = threadIdx.x;
  const int wid = tid >> 6, lane = tid & 63;
  const int wr = wid >> 1, wc = wid & 1;
  const int l15 = lane & 15, g = lane >> 4;

  // staging position p (16B units): tile row R=2*(p>>3)+((p>>2)&1),
  // source K col (bf16) = 8*((p&3)^((p>>3)&3))  [inverse of read swizzle]
  const int p0 = tid, p1 = tid + 256;
  const int r0_ = 2*(p0>>3) + ((p0>>2)&1), c0_ = 8*((p0&3) ^ ((p0>>3)&3));
  const int r1_ = 2*(p1>>3) + ((p1>>2)&1), c1_ = 8*((p1&3) ^ ((p1>>3)&3));
  const bf16* A00 = A + ((long)bm*128 + r0_)*NC + c0_;
  const bf16* A01 = A + ((long)bm*128 + r1_)*NC + c1_;
  const bf16* B00 = B + ((long)bn*128 + r0_)*NC + c0_;
  const bf16* B01 = B + ((long)bn*128 + r1_)*NC + c1_;

  auto stage = [&](int kt, int slot) {
    char* base = sm + slot*16384 + wid*1024;
    load_lds16(A00 + kt*32, base);
    load_lds16(A01 + kt*32, base + 4096);
    load_lds16(B00 + kt*32, base + 8192);
    load_lds16(B01 + kt*32, base + 12288);
  };

  auto aLoad = [&](int slot, int m) -> bf16x8 {
    int R = wr*64 + m*16 + l15;
    return *(const bf16x8*)(sm + slot*16384 + (R>>1)*128 + (R&1)*64
                            + ((g ^ ((R>>1)&3)) << 4));
  };
  auto bLoad = [&](int slot, int n) -> bf16x8 {
    int R = wc*64 + n*16 + l15;
    return *(const bf16x8*)(sm + slot*16384 + 8192 + (R>>1)*128 + (R&1)*64
                            + ((g ^ ((R>>1)&3)) << 4));
  };

  f32x4 acc[4][4] = {};

  stage(0, 0);
  asm volatile("s_waitcnt vmcnt(0)" ::: "memory");
  bar();

  int cur = 0;
  for (int kt = 0; kt < 16; ++kt) {
    if (kt < 15) stage(kt + 1, cur ^ 1);   // in flight across the MFMA phase
    bf16x8 af[4], bf_[4];
    #pragma unroll
    for (int m=0;m<4;++m) af[m] = aLoad(cur, m);
    #pragma unroll
    for (int n=0;n<4;++n) bf_[n] = bLoad(cur, n);
    __builtin_amdgcn_s_setprio(1);
    #pragma unroll
    for (int m=0;m<4;++m)
      #pragma unroll
      for (int n=0;n<4;++n)
        acc[m][n] = __builtin_amdgcn_mfma_f32_16x16x32_bf16(af[m], bf_[n], acc[m][n],0,0,0);
    __builtin_amdgcn_s_setprio(0);
    asm volatile("s_waitcnt vmcnt(0)" ::: "memory");   // next tile resident
    bar();                                             // all waves done with cur
    cur ^= 1;
  }

  const long rowb = (long)bm*128;
  const long colb = (long)bn*128;
  // bias into acc first (partials must include it)
  #pragma unroll
  for (int n=0;n<4;++n) {
    float bv = bias[colb + wc*64 + n*16 + l15];
    #pragma unroll
    for (int m=0;m<4;++m)
      #pragma unroll
      for (int q=0;q<4;++q) acc[m][n][q] += bv;
  }
  // per-wave 64-col partials: chunk = bn*2 + wc; shfl-only, no barrier
  #pragma unroll
  for (int m=0;m<4;++m)
    #pragma unroll
    for (int q=0;q<4;++q) {
      float mx = fmaxf(fmaxf(acc[m][0][q], acc[m][1][q]),
                       fmaxf(acc[m][2][q], acc[m][3][q]));
      #pragma unroll
      for (int msk=8;msk>=1;msk>>=1) mx = fmaxf(mx, __shfl_xor(mx, msk));
      float se = 0.f;
      #pragma unroll
      for (int n=0;n<4;++n) se += __expf(acc[m][n][q] - mx);
      #pragma unroll
      for (int msk=8;msk>=1;msk>>=1) se += __shfl_xor(se, msk);
      if (l15 == 0) {
        long row = rowb + wr*64 + m*16 + g*4 + q;
        pmax[row*NCHUNK + bn*2 + wc] = mx;
        psum[row*NCHUNK + bn*2 + wc] = se;
      }
    }
  // logits stores last: fire-and-forget (no sync after; wave retires)
  #pragma unroll
  for (int m=0;m<4;++m)
    #pragma unroll
    for (int n=0;n<4;++n) {
      long c = colb + wc*64 + n*16 + l15;
      #pragma unroll
      for (int q=0;q<4;++q) {
        long rr = rowb + wr*64 + m*16 + g*4 + q;
        __builtin_nontemporal_store(acc[m][n][q], &outf[rr*NV + c]);
      }
    }
}

// ---------------- PV combine + LN2: x1 = x0 + sum_c part[c]; h2 = LN(x1) ------
__global__ __launch_bounds__(64)
void pv_combine_ln_kernel(const float* __restrict__ part, const float* __restrict__ x0,
                          const float* __restrict__ gw, const float* __restrict__ bw,
                          float* __restrict__ x1, bf16* __restrict__ h2) {
  int row = blockIdx.x;
  int b = row >> 11, t = row & (NT-1);
  int lane = threadIdx.x;
  int nC = (t >> 9) + 1;
  const float* xr = x0 + (long)row*NC + lane*8;
  f32x4 a0 = *(const f32x4*)xr, a1 = *(const f32x4*)(xr+4);
  for (int c = 0; c < nC; ++c) {
    const float* pr = part + ((long)(c*4 + b)*NT + t)*NC + lane*8;
    a0 += *(const f32x4*)pr; a1 += *(const f32x4*)(pr+4);
  }
  float* o = x1 + (long)row*NC + lane*8;
  *(f32x4*)o = a0; *(f32x4*)(o+4) = a1;
  float v[8] = {a0.x,a0.y,a0.z,a0.w,a1.x,a1.y,a1.z,a1.w};
  float s = 0.f;
  #pragma unroll
  for (int j=0;j<8;++j) s += v[j];
  #pragma unroll
  for (int m=32;m>=1;m>>=1) s += __shfl_xor(s, m);
  float mu = s * (1.f/NC);
  float sq = 0.f;
  #pragma unroll
  for (int j=0;j<8;++j) { v[j] -= mu; sq += v[j]*v[j]; }
  #pragma unroll
  for (int m=32;m>=1;m>>=1) sq += __shfl_xor(sq, m);
  float rs = rsqrtf(sq * (1.f/NC) + LNEPS);
  const float* gp = gw + lane*8;
  const float* bp = bw + lane*8;
  f32x4 g0 = *(const f32x4*)gp, g1 = *(const f32x4*)(gp+4);
  f32x4 b0 = *(const f32x4*)bp, b1 = *(const f32x4*)(bp+4);
  float gg[8] = {g0.x,g0.y,g0.z,g0.w,g1.x,g1.y,g1.z,g1.w};
  float bb[8] = {b0.x,b0.y,b0.z,b0.w,b1.x,b1.y,b1.z,b1.w};
  bf16x8 oo;
  #pragma unroll
  for (int j=0;j<8;++j) oo[j] = (bf16)(v[j]*rs*gg[j] + bb[j]);
  *(bf16x8*)(h2 + (long)row*NC + lane*8) = oo;
}

// ---------------- FFN2 combine: x2 = bf16(x1 + b2 + sum_z part2[z]) ----------
__global__ __launch_bounds__(64)
void ffn2_combine_kernel(const float* __restrict__ part, const float* __restrict__ x1,
                         const float* __restrict__ b2, bf16* __restrict__ x2) {
  int row = blockIdx.x;
  int lane = threadIdx.x;
  const float* xr = x1 + (long)row*NC + lane*8;
  f32x4 a0 = *(const f32x4*)xr, a1 = *(const f32x4*)(xr+4);
  const float* br = b2 + lane*8;
  a0 += *(const f32x4*)br; a1 += *(const f32x4*)(br+4);
  #pragma unroll
  for (int z = 0; z < 4; ++z) {
    const float* pr = part + ((long)z*NROWS + row)*NC + lane*8;
    a0 += *(const f32x4*)pr; a1 += *(const f32x4*)(pr+4);
  }
  bf16x8 o;
  o[0]=(bf16)a0.x; o[1]=(bf16)a0.y; o[2]=(bf16)a0.z; o[3]=(bf16)a0.w;
  o[4]=(bf16)a1.x; o[5]=(bf16)a1.y; o[6]=(bf16)a1.z; o[7]=(bf16)a1.w;
  *(bf16x8*)(x2 + (long)row*NC + lane*8) = o;
}

// ---------------- loss pass 1 (500 chunks, 512 threads) ----------------
__global__ __launch_bounds__(512)
void loss1_kernel(const float* __restrict__ pmax, const float* __restrict__ psum,
                  const float* __restrict__ logits, const int* __restrict__ targets,
                  float* __restrict__ rowloss) {
  int row = blockIdx.x;
  int tid = threadIdx.x;
  int lane = tid & 63, wv = tid >> 6;
  float cm = (tid < NCHUNK) ? pmax[(long)row*NCHUNK + tid] : -1e30f;
  float cs = (tid < NCHUNK) ? psum[(long)row*NCHUNK + tid] : 0.f;
  float mx = cm;
  #pragma unroll
  for (int m=32;m>=1;m>>=1) mx = fmaxf(mx, __shfl_xor(mx, m));
  __shared__ float rm[8];
  if (lane == 0) rm[wv] = mx;
  __syncthreads();
  float M = rm[0];
  #pragma unroll
  for (int i=1;i<8;++i) M = fmaxf(M, rm[i]);
  float sc = cs * __expf(cm - M);
  #pragma unroll
  for (int m=32;m>=1;m>>=1) sc += __shfl_xor(sc, m);
  __shared__ float rs_[8];
  if (lane == 0) rs_[wv] = sc;
  __syncthreads();
  if (tid == 0) {
    float Sv = 0.f;
    #pragma unroll
    for (int i=0;i<8;++i) Sv += rs_[i];
    float lse = M + logf(Sv);
    int tgt = targets[row];
    float lg = logits[(long)row*NV + tgt];
    rowloss[row] = lse - lg;
  }
}

// ---------------- loss pass 2 ----------------
__global__ __launch_bounds__(256)
void loss2_kernel(const float* __restrict__ rowloss, float* __restrict__ out) {
  int tid = threadIdx.x;
  float s = 0.f;
  for (int i = tid; i < NROWS; i += 256) s += rowloss[i];
  #pragma unroll
  for (int m=32;m>=1;m>>=1) s += __shfl_xor(s, m);
  __shared__ float rs_[4];
  if ((tid & 63) == 0) rs_[tid>>6] = s;
  __syncthreads();
  if (tid == 0) out[0] = (rs_[0]+rs_[1]+rs_[2]+rs_[3]) * (1.f/NROWS);
}

// ---------------- launcher ----------------
extern "C" void kernel_launch(void* const* d_in, const int* in_sizes, int n_in,
                              void* d_out, int out_size, void* d_ws, size_t ws_size,
                              hipStream_t stream) {
  const int*   idx  = (const int*)d_in[0];
  const int*   tgt  = (const int*)d_in[1];
  const float* tok  = (const float*)d_in[2];
  const float* pos  = (const float*)d_in[3];
  const float* Wk   = (const float*)d_in[4];
  const float* Wq   = (const float*)d_in[5];
  const float* Wv   = (const float*)d_in[6];
  const float* W1   = (const float*)d_in[7];
  const float* b1   = (const float*)d_in[8];
  const float* W2   = (const float*)d_in[9];
  const float* b2   = (const float*)d_in[10];
  const float* g1   = (const float*)d_in[11];
  const float* be1  = (const float*)d_in[12];
  const float* g2   = (const float*)d_in[13];
  const float* be2  = (const float*)d_in[14];
  const float* Wlm  = (const float*)d_in[15];
  const float* blm  = (const float*)d_in[16];

  float* logits = (float*)d_out;
  float* loss   = logits + (long)NROWS*NV;

  char* w = (char*)d_ws;
  auto alloc = [&](size_t bytes) -> char* {
    char* p = w; w += (bytes + 255) & ~(size_t)255; return p;
  };
  bf16* wqkvb = (bf16*)alloc((size_t)3*NC*NC*2);
  bf16* w1b   = (bf16*)alloc((size_t)4*NC*NC*2);
  bf16* w2b   = (bf16*)alloc((size_t)4*NC*NC*2);
  bf16* wlmb  = (bf16*)alloc((size_t)NV*NC*2);
  float* x0   = (float*)alloc((size_t)NROWS*NC*4);
  bf16* h1b   = (bf16*)alloc((size_t)NROWS*NC*2);
  bf16* qkvb  = (bf16*)alloc((size_t)NROWS*3*NC*2);
  bf16* vtb   = (bf16*)alloc((size_t)NROWS*NC*2);
  float* Sb   = (float*)alloc((size_t)NB*NT*NT*4);      // P bf16 aliased; FFN2 partials alias
  float* pvp  = (float*)alloc((size_t)16*NT*NC*4);      // PV split-K partials
  float* x1   = (float*)alloc((size_t)NROWS*NC*4);
  bf16* h2b   = (bf16*)alloc((size_t)NROWS*NC*2);
  bf16* ffb   = (bf16*)alloc((size_t)NROWS*4*NC*2);
  bf16* x2b   = (bf16*)alloc((size_t)NROWS*NC*2);
  float* pmax = (float*)alloc((size_t)NROWS*NCHUNK*4);
  float* psum = (float*)alloc((size_t)NROWS*NCHUNK*4);
  float* rowloss = (float*)alloc((size_t)NROWS*4);
  float* ff2p = Sb;   // [4][8192][512] f32, aliases Sb (P dead by FFN2)

  hipFuncSetAttribute((const void*)gemm256<EPI_BF16,false,false,false>,
                      hipFuncAttributeMaxDynamicSharedMemorySize, SMEM_B);
  hipFuncSetAttribute((const void*)gemm256<EPI_F32,true,false,false>,
                      hipFuncAttributeMaxDynamicSharedMemorySize, SMEM_B);
  hipFuncSetAttribute((const void*)gemm256<EPI_F32,false,false,true>,
                      hipFuncAttributeMaxDynamicSharedMemorySize, SMEM_B);
  hipFuncSetAttribute((const void*)gemm256<EPI_F32,false,false,false>,
                      hipFuncAttributeMaxDynamicSharedMemorySize, SMEM_B);
  hipFuncSetAttribute((const void*)gemm256<EPI_BIAS_RELU_BF16,false,true,false>,
                      hipFuncAttributeMaxDynamicSharedMemorySize, SMEM_B);

  auto cvt = [&](const float* in, bf16* out, long n) {
    int n8 = (int)(n/8);
    int blocks = (n8 + 255)/256; if (blocks > 2048) blocks = 2048;
    cvt_kernel<<<blocks, 256, 0, stream>>>(in, out, n8);
  };
  cvt(Wq, wqkvb, (long)NC*NC);
  cvt(Wk, wqkvb + (long)NC*NC, (long)NC*NC);
  cvt(Wv, wqkvb + (long)2*NC*NC, (long)NC*NC);
  cvt(W1, w1b, (long)4*NC*NC);
  cvt(W2, w2b, (long)4*NC*NC);
  cvt(Wlm, wlmb, (long)NV*NC);

  embed_ln_kernel<<<NROWS, 64, 0, stream>>>(idx, tok, pos, g1, be1, x0, h1b);

  // fused QKV
  gemm256<EPI_BF16><<<dim3(6,32,1), 512, SMEM_B, stream>>>(
      h1b, wqkvb, 8, NC, NC, 0, 0, nullptr, qkvb, 3*NC, 0,
      nullptr, nullptr, 0, 0);

  transpose_kernel<<<dim3(NT/64, NC/64, NB), 256, 0, stream>>>(qkvb + 2*NC, 3*NC, vtb);

  // S = q k^T (per batch), causal block skip
  gemm256<EPI_F32,true><<<dim3(8,8,NB), 512, SMEM_B, stream>>>(
      qkvb, qkvb + NC, 8, 3*NC, 3*NC, (long)NT*3*NC, (long)NT*3*NC,
      Sb, nullptr, NT, (long)NT*NT,
      nullptr, nullptr, 0, 0);

  softmax_kernel<<<NROWS, 256, 0, stream>>>(Sb);

  // PV split-K over kv chunks: z = c*4 + b; partials -> pvp[z]
  gemm256<EPI_F32,false,false,true><<<dim3(2,8,16), 512, SMEM_B, stream>>>(
      (const bf16*)Sb, vtb, 8, 2*NT, NT, (long)NT*2*NT, (long)NC*NT,
      pvp, nullptr, NC, (long)NT*NC,
      nullptr, nullptr, 0, 0);

  // x1 = x0 + sum_c pvp; h2 = LN2(x1)
  pv_combine_ln_kernel<<<NROWS, 64, 0, stream>>>(pvp, x0, g2, be2, x1, h2b);

  // ff = relu(h2 W1^T + b1)
  gemm256<EPI_BIAS_RELU_BF16,false,true><<<dim3(32,8,1), 512, SMEM_B, stream>>>(
      h2b, w1b, 8, NC, NC, 0, 0, nullptr, ffb, 4*NC, 0,
      b1, nullptr, 0, 0);

  // FFN2 split-K x4
  gemm256<EPI_F32><<<dim3(2,32,4), 512, SMEM_B, stream>>>(
      ffb, w2b, 8, 4*NC, 4*NC, 512, 512,
      ff2p, nullptr, NC, (long)NROWS*NC,
      nullptr, nullptr, 0, 0);

  ffn2_combine_kernel<<<NROWS, 64, 0, stream>>>(ff2p, x1, b2, x2b);

  // LM head: BK=32 dbuf, 4 blocks/CU, barrier-free epilogue
  lmhead128<<<dim3(64, NV/128), 256, 0, stream>>>(x2b, wlmb, blm, logits, pmax, psum);

  loss1_kernel<<<NROWS, 512, 0, stream>>>(pmax, psum, logits, tgt, rowloss);
  loss2_kernel<<<1, 256, 0, stream>>>(rowloss, loss);
}

// Round 11
// 721.395 us; speedup vs baseline: 1.1222x; 1.0293x over previous
//
#include <hip/hip_runtime.h>

typedef __bf16 bf16;
typedef __bf16 bf16x8 __attribute__((ext_vector_type(8)));
typedef float  f32x4  __attribute__((ext_vector_type(4)));

#define NB 4
#define NT 2048
#define NC 512
#define NV 32000
#define NROWS (NB*NT)          // 8192
#define NCHUNK 500             // 64-col chunks for LM-head partials
#define LNEPS 1e-5f
#define SMEM_B 131072

static __device__ __forceinline__ void load_lds16(const bf16* g, char* l) {
  __builtin_amdgcn_global_load_lds(
      (const __attribute__((address_space(1))) void*)g,
      (__attribute__((address_space(3))) void*)l, 16, 0, 0);
}

static __device__ __forceinline__ void bar() {
  asm volatile("" ::: "memory");
  __builtin_amdgcn_s_barrier();
  asm volatile("" ::: "memory");
}

// ---------------- f32 -> bf16 convert ----------------
__global__ __launch_bounds__(256)
void cvt_kernel(const float* __restrict__ in, bf16* __restrict__ out, int n8) {
  long i = (long)blockIdx.x * 256 + threadIdx.x;
  long stride = (long)gridDim.x * 256;
  for (; i < n8; i += stride) {
    const float* p = in + i * 8;
    f32x4 a = *(const f32x4*)p;
    f32x4 b = *(const f32x4*)(p + 4);
    bf16x8 o;
    o[0]=(bf16)a.x; o[1]=(bf16)a.y; o[2]=(bf16)a.z; o[3]=(bf16)a.w;
    o[4]=(bf16)b.x; o[5]=(bf16)b.y; o[6]=(bf16)b.z; o[7]=(bf16)b.w;
    *(bf16x8*)(out + i*8) = o;
  }
}

// ---------------- fused embedding + layernorm1 ----------------
__global__ __launch_bounds__(64)
void embed_ln_kernel(const int* __restrict__ idx, const float* __restrict__ tok,
                     const float* __restrict__ pos, const float* __restrict__ gw,
                     const float* __restrict__ bw,
                     float* __restrict__ x0, bf16* __restrict__ h1) {
  int row = blockIdx.x;
  int t = row & (NT-1);
  int id = idx[row];
  int lane = threadIdx.x;
  const float* tr = tok + (long)id*NC + lane*8;
  const float* pr = pos + (long)t*NC + lane*8;
  f32x4 a0 = *(const f32x4*)tr, a1 = *(const f32x4*)(tr+4);
  f32x4 p0 = *(const f32x4*)pr, p1 = *(const f32x4*)(pr+4);
  f32x4 r0 = a0 + p0, r1 = a1 + p1;
  float* o = x0 + (long)row*NC + lane*8;
  *(f32x4*)o = r0; *(f32x4*)(o+4) = r1;
  float v[8] = {r0.x,r0.y,r0.z,r0.w,r1.x,r1.y,r1.z,r1.w};
  float s = 0.f;
  #pragma unroll
  for (int j=0;j<8;++j) s += v[j];
  #pragma unroll
  for (int m=32;m>=1;m>>=1) s += __shfl_xor(s, m);
  float mu = s * (1.f/NC);
  float sq = 0.f;
  #pragma unroll
  for (int j=0;j<8;++j) { v[j] -= mu; sq += v[j]*v[j]; }
  #pragma unroll
  for (int m=32;m>=1;m>>=1) sq += __shfl_xor(sq, m);
  float rs = rsqrtf(sq * (1.f/NC) + LNEPS);
  const float* gp = gw + lane*8;
  const float* bp = bw + lane*8;
  f32x4 g0 = *(const f32x4*)gp, g1 = *(const f32x4*)(gp+4);
  f32x4 b0 = *(const f32x4*)bp, b1 = *(const f32x4*)(bp+4);
  float gg[8] = {g0.x,g0.y,g0.z,g0.w,g1.x,g1.y,g1.z,g1.w};
  float bb[8] = {b0.x,b0.y,b0.z,b0.w,b1.x,b1.y,b1.z,b1.w};
  bf16x8 oo;
  #pragma unroll
  for (int j=0;j<8;++j) oo[j] = (bf16)(v[j]*rs*gg[j] + bb[j]);
  *(bf16x8*)(h1 + (long)row*NC + lane*8) = oo;
}

// ---------------- transpose v[b][t][c] (stride ldv) -> vt[b][c][t] ----------------
__global__ __launch_bounds__(256)
void transpose_kernel(const bf16* __restrict__ v, long ldv, bf16* __restrict__ vt) {
  __shared__ bf16 tile[64][66];
  int b = blockIdx.z;
  int t0 = blockIdx.x*64, c0 = blockIdx.y*64;
  int tid = threadIdx.x;
  int r = tid >> 2, ch = (tid & 3) * 16;
  const bf16* src = v + ((long)b*NT + t0 + r)*ldv + c0 + ch;
  #pragma unroll
  for (int i=0;i<16;++i) tile[r][ch+i] = src[i];
  __syncthreads();
  bf16x8 o0, o1;
  #pragma unroll
  for (int i=0;i<8;++i) o0[i] = tile[ch+i][r];
  #pragma unroll
  for (int i=0;i<8;++i) o1[i] = tile[ch+8+i][r];
  bf16* dst = vt + ((long)b*NC + c0 + r)*NT + t0 + ch;
  *(bf16x8*)dst = o0;
  *(bf16x8*)(dst+8) = o1;
}

// ---------------- causal softmax row: S f32 -> P bf16 (aliased into S) ----------------
__global__ __launch_bounds__(256)
void softmax_kernel(float* __restrict__ S) {
  const int row = blockIdx.x;
  const int t = row & (NT-1);
  const int tid = threadIdx.x;
  float* sr = S + (long)row*NT;
  bf16* pr = (bf16*)S + (long)row*(2*NT);
  const float scale = 0.044194173824159216f;
  f32x4 v0 = *(const f32x4*)(sr + tid*8);
  f32x4 v1 = *(const f32x4*)(sr + tid*8 + 4);
  float v[8] = {v0.x,v0.y,v0.z,v0.w,v1.x,v1.y,v1.z,v1.w};
  int cb = tid*8;
  float mx = -1e30f;
  #pragma unroll
  for (int j=0;j<8;++j) {
    v[j] = (cb + j <= t) ? v[j]*scale : -1e30f;
    mx = fmaxf(mx, v[j]);
  }
  __shared__ float redm[4];
  #pragma unroll
  for (int m=32;m>=1;m>>=1) mx = fmaxf(mx, __shfl_xor(mx, m));
  if ((tid & 63) == 0) redm[tid>>6] = mx;
  __syncthreads();
  mx = fmaxf(fmaxf(redm[0],redm[1]), fmaxf(redm[2],redm[3]));
  float e[8]; float s = 0.f;
  #pragma unroll
  for (int j=0;j<8;++j) { e[j] = (cb + j <= t) ? __expf(v[j]-mx) : 0.f; s += e[j]; }
  __shared__ float reds[4];
  #pragma unroll
  for (int m=32;m>=1;m>>=1) s += __shfl_xor(s, m);
  if ((tid & 63) == 0) reds[tid>>6] = s;
  __syncthreads();
  s = reds[0]+reds[1]+reds[2]+reds[3];
  float inv = 1.f/s;
  bf16x8 o;
  #pragma unroll
  for (int j=0;j<8;++j) o[j] = (bf16)(e[j]*inv);
  *(bf16x8*)(pr + cb) = o;
}

// ======== 256x256-tile 8-phase GEMM: out[M,N] = A[M,K] * B[N,K]^T ========
enum { EPI_F32=0, EPI_BF16=1, EPI_BIAS_RELU_BF16=2, EPI_BIAS_RES_BF16=3, EPI_RES_F32=4 };

template<int EPI, bool CAUSAL=false, bool SWAP=false, bool KCHUNK=false>
__global__ __launch_bounds__(512,2)
void gemm256(const bf16* __restrict__ A, const bf16* __restrict__ B, int nkt,
             long lda, long ldb, long sAb, long sBb,
             float* __restrict__ outf, bf16* __restrict__ outb, long ldo, long sOb,
             const float* __restrict__ bias,
             const float* __restrict__ res, long ldr, long sRb) {
  extern __shared__ char smem[];
  int bn, bm;
  if constexpr (SWAP) { bm = blockIdx.x; bn = blockIdx.y; }
  else               { bn = blockIdx.x; bm = blockIdx.y; }
  const int bz = blockIdx.z;
  if constexpr (CAUSAL) { if (bn > bm) return; }
  int nkt_eff = nkt;
  int bzAB = bz;
  long kOff = 0;
  if constexpr (KCHUNK) {
    int c = bz >> 2; bzAB = bz & 3;
    int lim = (bm+1)*4 - c*8;
    if (lim <= 0) return;
    if (lim < nkt_eff) nkt_eff = lim;
    kOff = (long)c*512;
  }

  const int tid = threadIdx.x;
  const int wid = tid >> 6, lane = tid & 63;
  const int wr = wid >> 2, wc = wid & 3;
  const int l15 = lane & 15, g = lane >> 4;

  const bf16* Ab = A + (long)bzAB*sAb + kOff + (long)bm*256*lda;
  const bf16* Bb = B + (long)bzAB*sBb + kOff + (long)bn*256*ldb;

  const int colsw = 8 * ((tid & 7) ^ ((tid >> 3) & 7));
  const bf16* A0 = Ab + (long)(tid >> 3)*lda + colsw;
  const bf16* B0 = Bb + (long)(tid >> 3)*ldb + colsw;

  auto stage = [&](int ab, int t, int h, int slot) {
    char* dst = smem + slot*65536 + ab*32768 + h*16384 + wid*1024;
    const bf16* s0 = (ab ? B0 : A0) + (long)(h*128)*(ab ? ldb : lda) + (long)t*64;
    load_lds16(s0, dst);
    load_lds16(s0 + 64*(ab ? ldb : lda), dst + 8192);
  };

  const char* sm = smem;
  auto aLoad = [&](int slot, int m, int kk) -> bf16x8 {
    int row = m*16 + l15;
    int b = row*128 + ((kk*64 + g*16) ^ ((row & 7) << 4));
    return *(const bf16x8*)(sm + slot*65536 + wr*16384 + b);
  };
  auto bLoad = [&](int slot, int n, int kk) -> bf16x8 {
    int row = (wc & 1)*64 + n*16 + l15;
    int b = row*128 + ((kk*64 + g*16) ^ ((row & 7) << 4));
    return *(const bf16x8*)(sm + slot*65536 + 32768 + (wc >> 1)*16384 + b);
  };

  f32x4 acc[8][4] = {};

  stage(0, 0, 0, 0);
  stage(0, 0, 1, 0);
  stage(1, 0, 0, 0);
  stage(1, 0, 1, 0);
  stage(0, 1, 0, 1);
  asm volatile("s_waitcnt vmcnt(2)" ::: "memory");
  bar();

  const int niter = nkt_eff >> 1;
  for (int it = 0; it < niter; ++it) {
    const int t0 = 2*it, t1 = 2*it + 1;
    const int tn0 = (t0+2 < nkt_eff) ? t0+2 : nkt_eff-1;
    const int tn1 = (t1+2 < nkt_eff) ? t1+2 : nkt_eff-1;
    bf16x8 a0[4][2], a1[4][2], b0[2][2], b1[2][2];

    // P1
    #pragma unroll
    for (int m=0;m<4;++m) { a0[m][0]=aLoad(0,m,0); a0[m][1]=aLoad(0,m,1); }
    #pragma unroll
    for (int n=0;n<2;++n) { b0[n][0]=bLoad(0,n,0); b0[n][1]=bLoad(0,n,1); }
    stage(0, t1, 1, 1);
    bar();
    __builtin_amdgcn_s_setprio(1);
    #pragma unroll
    for (int m=0;m<4;++m)
      #pragma unroll
      for (int n=0;n<2;++n) {
        acc[m][n] = __builtin_amdgcn_mfma_f32_16x16x32_bf16(a0[m][0], b0[n][0], acc[m][n],0,0,0);
        acc[m][n] = __builtin_amdgcn_mfma_f32_16x16x32_bf16(a0[m][1], b0[n][1], acc[m][n],0,0,0);
      }
    __builtin_amdgcn_s_setprio(0);
    bar();
    // P2
    #pragma unroll
    for (int n=0;n<2;++n) { b1[n][0]=bLoad(0,n+2,0); b1[n][1]=bLoad(0,n+2,1); }
    stage(1, t1, 0, 1);
    bar();
    __builtin_amdgcn_s_setprio(1);
    #pragma unroll
    for (int m=0;m<4;++m)
      #pragma unroll
      for (int n=0;n<2;++n) {
        acc[m][n+2] = __builtin_amdgcn_mfma_f32_16x16x32_bf16(a0[m][0], b1[n][0], acc[m][n+2],0,0,0);
        acc[m][n+2] = __builtin_amdgcn_mfma_f32_16x16x32_bf16(a0[m][1], b1[n][1], acc[m][n+2],0,0,0);
      }
    __builtin_amdgcn_s_setprio(0);
    bar();
    // P3
    #pragma unroll
    for (int m=0;m<4;++m) { a1[m][0]=aLoad(0,m+4,0); a1[m][1]=aLoad(0,m+4,1); }
    stage(1, t1, 1, 1);
    bar();
    __builtin_amdgcn_s_setprio(1);
    #pragma unroll
    for (int m=0;m<4;++m)
      #pragma unroll
      for (int n=0;n<2;++n) {
        acc[m+4][n+2] = __builtin_amdgcn_mfma_f32_16x16x32_bf16(a1[m][0], b1[n][0], acc[m+4][n+2],0,0,0);
        acc[m+4][n+2] = __builtin_amdgcn_mfma_f32_16x16x32_bf16(a1[m][1], b1[n][1], acc[m+4][n+2],0,0,0);
      }
    __builtin_amdgcn_s_setprio(0);
    bar();
    // P4
    stage(0, tn0, 0, 0);
    asm volatile("s_waitcnt vmcnt(2)" ::: "memory");
    bar();
    __builtin_amdgcn_s_setprio(1);
    #pragma unroll
    for (int m=0;m<4;++m)
      #pragma unroll
      for (int n=0;n<2;++n) {
        acc[m+4][n] = __builtin_amdgcn_mfma_f32_16x16x32_bf16(a1[m][0], b0[n][0], acc[m+4][n],0,0,0);
        acc[m+4][n] = __builtin_amdgcn_mfma_f32_16x16x32_bf16(a1[m][1], b0[n][1], acc[m+4][n],0,0,0);
      }
    __builtin_amdgcn_s_setprio(0);
    bar();
    // P5
    #pragma unroll
    for (int m=0;m<4;++m) { a0[m][0]=aLoad(1,m,0); a0[m][1]=aLoad(1,m,1); }
    #pragma unroll
    for (int n=0;n<2;++n) { b0[n][0]=bLoad(1,n,0); b0[n][1]=bLoad(1,n,1); }
    stage(0, tn0, 1, 0);
    bar();
    __builtin_amdgcn_s_setprio(1);
    #pragma unroll
    for (int m=0;m<4;++m)
      #pragma unroll
      for (int n=0;n<2;++n) {
        acc[m][n] = __builtin_amdgcn_mfma_f32_16x16x32_bf16(a0[m][0], b0[n][0], acc[m][n],0,0,0);
        acc[m][n] = __builtin_amdgcn_mfma_f32_16x16x32_bf16(a0[m][1], b0[n][1], acc[m][n],0,0,0);
      }
    __builtin_amdgcn_s_setprio(0);
    bar();
    // P6
    #pragma unroll
    for (int n=0;n<2;++n) { b1[n][0]=bLoad(1,n+2,0); b1[n][1]=bLoad(1,n+2,1); }
    stage(1, tn0, 0, 0);
    bar();
    __builtin_amdgcn_s_setprio(1);
    #pragma unroll
    for (int m=0;m<4;++m)
      #pragma unroll
      for (int n=0;n<2;++n) {
        acc[m][n+2] = __builtin_amdgcn_mfma_f32_16x16x32_bf16(a0[m][0], b1[n][0], acc[m][n+2],0,0,0);
        acc[m][n+2] = __builtin_amdgcn_mfma_f32_16x16x32_bf16(a0[m][1], b1[n][1], acc[m][n+2],0,0,0);
      }
    __builtin_amdgcn_s_setprio(0);
    bar();
    // P7
    #pragma unroll
    for (int m=0;m<4;++m) { a1[m][0]=aLoad(1,m+4,0); a1[m][1]=aLoad(1,m+4,1); }
    stage(1, tn0, 1, 0);
    bar();
    __builtin_amdgcn_s_setprio(1);
    #pragma unroll
    for (int m=0;m<4;++m)
      #pragma unroll
      for (int n=0;n<2;++n) {
        acc[m+4][n+2] = __builtin_amdgcn_mfma_f32_16x16x32_bf16(a1[m][0], b1[n][0], acc[m+4][n+2],0,0,0);
        acc[m+4][n+2] = __builtin_amdgcn_mfma_f32_16x16x32_bf16(a1[m][1], b1[n][1], acc[m+4][n+2],0,0,0);
      }
    __builtin_amdgcn_s_setprio(0);
    bar();
    // P8
    stage(0, tn1, 0, 1);
    asm volatile("s_waitcnt vmcnt(2)" ::: "memory");
    bar();
    __builtin_amdgcn_s_setprio(1);
    #pragma unroll
    for (int m=0;m<4;++m)
      #pragma unroll
      for (int n=0;n<2;++n) {
        acc[m+4][n] = __builtin_amdgcn_mfma_f32_16x16x32_bf16(a1[m][0], b0[n][0], acc[m+4][n],0,0,0);
        acc[m+4][n] = __builtin_amdgcn_mfma_f32_16x16x32_bf16(a1[m][1], b0[n][1], acc[m+4][n],0,0,0);
      }
    __builtin_amdgcn_s_setprio(0);
    bar();
  }

  const long rowbase = (long)bm*256 + wr*128;
  const long colbase = (long)bn*256 + wc*64;

  #pragma unroll
  for (int m=0;m<8;++m)
    #pragma unroll
    for (int n=0;n<4;++n) {
      long c = colbase + n*16 + l15;
      #pragma unroll
      for (int q_=0;q_<4;++q_) {
        long rr = rowbase + m*16 + g*4 + q_;
        float v = acc[m][n][q_];
        if constexpr (EPI == EPI_F32) {
          outf[(long)bz*sOb + rr*ldo + c] = v;
        } else if constexpr (EPI == EPI_BF16) {
          outb[(long)bz*sOb + rr*ldo + c] = (bf16)v;
        } else if constexpr (EPI == EPI_BIAS_RELU_BF16) {
          outb[rr*ldo + c] = (bf16)fmaxf(v + bias[c], 0.f);
        } else if constexpr (EPI == EPI_BIAS_RES_BF16) {
          outb[rr*ldo + c] = (bf16)(v + bias[c] + res[rr*ldr + c]);
        } else if constexpr (EPI == EPI_RES_F32) {
          outf[(long)bz*sOb + rr*ldo + c] = v + res[(long)bz*sRb + rr*ldr + c];
        }
      }
    }
}

// ======== LM head: 128x128 tile, BK=32 dbuf, 4 blocks/CU ========
// R10 structure + LDS-TRANSPOSED EPILOGUE: the scattered per-dword logits
// stores (4x64B half-lines per instr) capped write BW at ~2 TB/s (R9: 1.2GB /
// 650us). Each wave now dumps its 16x64 f32 sub-block to a private 4KB LDS
// region (no barrier: own region, same-wave DS ordering) and stores f32x4
// row-major: 4 rows x 256B contiguous aligned per instr = full 128B lines.
__global__ __launch_bounds__(256,4)
void lmhead128(const bf16* __restrict__ A, const bf16* __restrict__ B,
               const float* __restrict__ bias, float* __restrict__ outf,
               float* __restrict__ pmax, float* __restrict__ psum) {
  __shared__ char sm[32768];   // 2 slots x (A 8KB + B 8KB); epilogue reuses 16KB
  const int bm = blockIdx.x, bn = blockIdx.y;   // bm fast: panel shared by 64 blocks
  const int tid = threadIdx.x;
  const int wid = tid >> 6, lane = tid & 63;
  const int wr = wid >> 1, wc = wid & 1;
  const int l15 = lane & 15, g = lane >> 4;

  // staging position p (16B units): tile row R=2*(p>>3)+((p>>2)&1),
  // source K col (bf16) = 8*((p&3)^((p>>3)&3))  [inverse of read swizzle]
  const int p0 = tid, p1 = tid + 256;
  const int r0_ = 2*(p0>>3) + ((p0>>2)&1), c0_ = 8*((p0&3) ^ ((p0>>3)&3));
  const int r1_ = 2*(p1>>3) + ((p1>>2)&1), c1_ = 8*((p1&3) ^ ((p1>>3)&3));
  const bf16* A00 = A + ((long)bm*128 + r0_)*NC + c0_;
  const bf16* A01 = A + ((long)bm*128 + r1_)*NC + c1_;
  const bf16* B00 = B + ((long)bn*128 + r0_)*NC + c0_;
  const bf16* B01 = B + ((long)bn*128 + r1_)*NC + c1_;

  auto stage = [&](int kt, int slot) {
    char* base = sm + slot*16384 + wid*1024;
    load_lds16(A00 + kt*32, base);
    load_lds16(A01 + kt*32, base + 4096);
    load_lds16(B00 + kt*32, base + 8192);
    load_lds16(B01 + kt*32, base + 12288);
  };

  auto aLoad = [&](int slot, int m) -> bf16x8 {
    int R = wr*64 + m*16 + l15;
    return *(const bf16x8*)(sm + slot*16384 + (R>>1)*128 + (R&1)*64
                            + ((g ^ ((R>>1)&3)) << 4));
  };
  auto bLoad = [&](int slot, int n) -> bf16x8 {
    int R = wc*64 + n*16 + l15;
    return *(const bf16x8*)(sm + slot*16384 + 8192 + (R>>1)*128 + (R&1)*64
                            + ((g ^ ((R>>1)&3)) << 4));
  };

  f32x4 acc[4][4] = {};

  stage(0, 0);
  asm volatile("s_waitcnt vmcnt(0)" ::: "memory");
  bar();

  int cur = 0;
  for (int kt = 0; kt < 16; ++kt) {
    if (kt < 15) stage(kt + 1, cur ^ 1);   // in flight across the MFMA phase
    bf16x8 af[4], bf_[4];
    #pragma unroll
    for (int m=0;m<4;++m) af[m] = aLoad(cur, m);
    #pragma unroll
    for (int n=0;n<4;++n) bf_[n] = bLoad(cur, n);
    __builtin_amdgcn_s_setprio(1);
    #pragma unroll
    for (int m=0;m<4;++m)
      #pragma unroll
      for (int n=0;n<4;++n)
        acc[m][n] = __builtin_amdgcn_mfma_f32_16x16x32_bf16(af[m], bf_[n], acc[m][n],0,0,0);
    __builtin_amdgcn_s_setprio(0);
    asm volatile("s_waitcnt vmcnt(0)" ::: "memory");   // next tile resident
    bar();                                             // all waves done with cur
    cur ^= 1;
  }

  const long rowb = (long)bm*128;
  const long colb = (long)bn*128;
  // bias into acc first (partials must include it)
  #pragma unroll
  for (int n=0;n<4;++n) {
    float bv = bias[colb + wc*64 + n*16 + l15];
    #pragma unroll
    for (int m=0;m<4;++m)
      #pragma unroll
      for (int q=0;q<4;++q) acc[m][n][q] += bv;
  }
  // per-wave 64-col softmax partials: chunk = bn*2 + wc; shfl-only, no barrier
  #pragma unroll
  for (int m=0;m<4;++m)
    #pragma unroll
    for (int q=0;q<4;++q) {
      float mx = fmaxf(fmaxf(acc[m][0][q], acc[m][1][q]),
                       fmaxf(acc[m][2][q], acc[m][3][q]));
      #pragma unroll
      for (int msk=8;msk>=1;msk>>=1) mx = fmaxf(mx, __shfl_xor(mx, msk));
      float se = 0.f;
      #pragma unroll
      for (int n=0;n<4;++n) se += __expf(acc[m][n][q] - mx);
      #pragma unroll
      for (int msk=8;msk>=1;msk>>=1) se += __shfl_xor(se, msk);
      if (l15 == 0) {
        long row = rowb + wr*64 + m*16 + g*4 + q;
        pmax[row*NCHUNK + bn*2 + wc] = mx;
        psum[row*NCHUNK + bn*2 + wc] = se;
      }
    }
  // LDS-transposed logits stores: per-wave private 4KB buffer [16 rows][64 f32]
  float* lbuf = (float*)(sm + wid*4096);
  #pragma unroll
  for (int m=0;m<4;++m) {
    #pragma unroll
    for (int n=0;n<4;++n)
      #pragma unroll
      for (int q=0;q<4;++q)
        lbuf[(g*4+q)*64 + n*16 + l15] = acc[m][n][q];
    // same-wave DS ordering + compiler lgkmcnt handle write->read dependence
    #pragma unroll
    for (int p=0;p<4;++p) {
      f32x4 v = *(const f32x4*)&lbuf[(p*4+g)*64 + l15*4];
      long row = rowb + wr*64 + m*16 + p*4 + g;
      long col = colb + wc*64 + l15*4;
      __builtin_nontemporal_store(v, (f32x4*)&outf[row*NV + col]);
    }
  }
}

// ---------------- PV combine + LN2: x1 = x0 + sum_c part[c]; h2 = LN(x1) ------
__global__ __launch_bounds__(64)
void pv_combine_ln_kernel(const float* __restrict__ part, const float* __restrict__ x0,
                          const float* __restrict__ gw, const float* __restrict__ bw,
                          float* __restrict__ x1, bf16* __restrict__ h2) {
  int row = blockIdx.x;
  int b = row >> 11, t = row & (NT-1);
  int lane = threadIdx.x;
  int nC = (t >> 9) + 1;
  const float* xr = x0 + (long)row*NC + lane*8;
  f32x4 a0 = *(const f32x4*)xr, a1 = *(const f32x4*)(xr+4);
  for (int c = 0; c < nC; ++c) {
    const float* pr = part + ((long)(c*4 + b)*NT + t)*NC + lane*8;
    a0 += *(const f32x4*)pr; a1 += *(const f32x4*)(pr+4);
  }
  float* o = x1 + (long)row*NC + lane*8;
  *(f32x4*)o = a0; *(f32x4*)(o+4) = a1;
  float v[8] = {a0.x,a0.y,a0.z,a0.w,a1.x,a1.y,a1.z,a1.w};
  float s = 0.f;
  #pragma unroll
  for (int j=0;j<8;++j) s += v[j];
  #pragma unroll
  for (int m=32;m>=1;m>>=1) s += __shfl_xor(s, m);
  float mu = s * (1.f/NC);
  float sq = 0.f;
  #pragma unroll
  for (int j=0;j<8;++j) { v[j] -= mu; sq += v[j]*v[j]; }
  #pragma unroll
  for (int m=32;m>=1;m>>=1) sq += __shfl_xor(sq, m);
  float rs = rsqrtf(sq * (1.f/NC) + LNEPS);
  const float* gp = gw + lane*8;
  const float* bp = bw + lane*8;
  f32x4 g0 = *(const f32x4*)gp, g1 = *(const f32x4*)(gp+4);
  f32x4 b0 = *(const f32x4*)bp, b1 = *(const f32x4*)(bp+4);
  float gg[8] = {g0.x,g0.y,g0.z,g0.w,g1.x,g1.y,g1.z,g1.w};
  float bb[8] = {b0.x,b0.y,b0.z,b0.w,b1.x,b1.y,b1.z,b1.w};
  bf16x8 oo;
  #pragma unroll
  for (int j=0;j<8;++j) oo[j] = (bf16)(v[j]*rs*gg[j] + bb[j]);
  *(bf16x8*)(h2 + (long)row*NC + lane*8) = oo;
}

// ---------------- FFN2 combine: x2 = bf16(x1 + b2 + sum_z part2[z]) ----------
__global__ __launch_bounds__(64)
void ffn2_combine_kernel(const float* __restrict__ part, const float* __restrict__ x1,
                         const float* __restrict__ b2, bf16* __restrict__ x2) {
  int row = blockIdx.x;
  int lane = threadIdx.x;
  const float* xr = x1 + (long)row*NC + lane*8;
  f32x4 a0 = *(const f32x4*)xr, a1 = *(const f32x4*)(xr+4);
  const float* br = b2 + lane*8;
  a0 += *(const f32x4*)br; a1 += *(const f32x4*)(br+4);
  #pragma unroll
  for (int z = 0; z < 4; ++z) {
    const float* pr = part + ((long)z*NROWS + row)*NC + lane*8;
    a0 += *(const f32x4*)pr; a1 += *(const f32x4*)(pr+4);
  }
  bf16x8 o;
  o[0]=(bf16)a0.x; o[1]=(bf16)a0.y; o[2]=(bf16)a0.z; o[3]=(bf16)a0.w;
  o[4]=(bf16)a1.x; o[5]=(bf16)a1.y; o[6]=(bf16)a1.z; o[7]=(bf16)a1.w;
  *(bf16x8*)(x2 + (long)row*NC + lane*8) = o;
}

// ---------------- loss pass 1 (500 chunks, 512 threads) ----------------
__global__ __launch_bounds__(512)
void loss1_kernel(const float* __restrict__ pmax, const float* __restrict__ psum,
                  const float* __restrict__ logits, const int* __restrict__ targets,
                  float* __restrict__ rowloss) {
  int row = blockIdx.x;
  int tid = threadIdx.x;
  int lane = tid & 63, wv = tid >> 6;
  float cm = (tid < NCHUNK) ? pmax[(long)row*NCHUNK + tid] : -1e30f;
  float cs = (tid < NCHUNK) ? psum[(long)row*NCHUNK + tid] : 0.f;
  float mx = cm;
  #pragma unroll
  for (int m=32;m>=1;m>>=1) mx = fmaxf(mx, __shfl_xor(mx, m));
  __shared__ float rm[8];
  if (lane == 0) rm[wv] = mx;
  __syncthreads();
  float M = rm[0];
  #pragma unroll
  for (int i=1;i<8;++i) M = fmaxf(M, rm[i]);
  float sc = cs * __expf(cm - M);
  #pragma unroll
  for (int m=32;m>=1;m>>=1) sc += __shfl_xor(sc, m);
  __shared__ float rs_[8];
  if (lane == 0) rs_[wv] = sc;
  __syncthreads();
  if (tid == 0) {
    float Sv = 0.f;
    #pragma unroll
    for (int i=0;i<8;++i) Sv += rs_[i];
    float lse = M + logf(Sv);
    int tgt = targets[row];
    float lg = logits[(long)row*NV + tgt];
    rowloss[row] = lse - lg;
  }
}

// ---------------- loss pass 2 ----------------
__global__ __launch_bounds__(256)
void loss2_kernel(const float* __restrict__ rowloss, float* __restrict__ out) {
  int tid = threadIdx.x;
  float s = 0.f;
  for (int i = tid; i < NROWS; i += 256) s += rowloss[i];
  #pragma unroll
  for (int m=32;m>=1;m>>=1) s += __shfl_xor(s, m);
  __shared__ float rs_[4];
  if ((tid & 63) == 0) rs_[tid>>6] = s;
  __syncthreads();
  if (tid == 0) out[0] = (rs_[0]+rs_[1]+rs_[2]+rs_[3]) * (1.f/NROWS);
}

// ---------------- launcher ----------------
extern "C" void kernel_launch(void* const* d_in, const int* in_sizes, int n_in,
                              void* d_out, int out_size, void* d_ws, size_t ws_size,
                              hipStream_t stream) {
  const int*   idx  = (const int*)d_in[0];
  const int*   tgt  = (const int*)d_in[1];
  const float* tok  = (const float*)d_in[2];
  const float* pos  = (const float*)d_in[3];
  const float* Wk   = (const float*)d_in[4];
  const float* Wq   = (const float*)d_in[5];
  const float* Wv   = (const float*)d_in[6];
  const float* W1   = (const float*)d_in[7];
  const float* b1   = (const float*)d_in[8];
  const float* W2   = (const float*)d_in[9];
  const float* b2   = (const float*)d_in[10];
  const float* g1   = (const float*)d_in[11];
  const float* be1  = (const float*)d_in[12];
  const float* g2   = (const float*)d_in[13];
  const float* be2  = (const float*)d_in[14];
  const float* Wlm  = (const float*)d_in[15];
  const float* blm  = (const float*)d_in[16];

  float* logits = (float*)d_out;
  float* loss   = logits + (long)NROWS*NV;

  char* w = (char*)d_ws;
  auto alloc = [&](size_t bytes) -> char* {
    char* p = w; w += (bytes + 255) & ~(size_t)255; return p;
  };
  bf16* wqkvb = (bf16*)alloc((size_t)3*NC*NC*2);
  bf16* w1b   = (bf16*)alloc((size_t)4*NC*NC*2);
  bf16* w2b   = (bf16*)alloc((size_t)4*NC*NC*2);
  bf16* wlmb  = (bf16*)alloc((size_t)NV*NC*2);
  float* x0   = (float*)alloc((size_t)NROWS*NC*4);
  bf16* h1b   = (bf16*)alloc((size_t)NROWS*NC*2);
  bf16* qkvb  = (bf16*)alloc((size_t)NROWS*3*NC*2);
  bf16* vtb   = (bf16*)alloc((size_t)NROWS*NC*2);
  float* Sb   = (float*)alloc((size_t)NB*NT*NT*4);      // P bf16 aliased; FFN2 partials alias
  float* pvp  = (float*)alloc((size_t)16*NT*NC*4);      // PV split-K partials
  float* x1   = (float*)alloc((size_t)NROWS*NC*4);
  bf16* h2b   = (bf16*)alloc((size_t)NROWS*NC*2);
  bf16* ffb   = (bf16*)alloc((size_t)NROWS*4*NC*2);
  bf16* x2b   = (bf16*)alloc((size_t)NROWS*NC*2);
  float* pmax = (float*)alloc((size_t)NROWS*NCHUNK*4);
  float* psum = (float*)alloc((size_t)NROWS*NCHUNK*4);
  float* rowloss = (float*)alloc((size_t)NROWS*4);
  float* ff2p = Sb;   // [4][8192][512] f32, aliases Sb (P dead by FFN2)

  hipFuncSetAttribute((const void*)gemm256<EPI_BF16,false,false,false>,
                      hipFuncAttributeMaxDynamicSharedMemorySize, SMEM_B);
  hipFuncSetAttribute((const void*)gemm256<EPI_F32,true,false,false>,
                      hipFuncAttributeMaxDynamicSharedMemorySize, SMEM_B);
  hipFuncSetAttribute((const void*)gemm256<EPI_F32,false,false,true>,
                      hipFuncAttributeMaxDynamicSharedMemorySize, SMEM_B);
  hipFuncSetAttribute((const void*)gemm256<EPI_F32,false,false,false>,
                      hipFuncAttributeMaxDynamicSharedMemorySize, SMEM_B);
  hipFuncSetAttribute((const void*)gemm256<EPI_BIAS_RELU_BF16,false,true,false>,
                      hipFuncAttributeMaxDynamicSharedMemorySize, SMEM_B);

  auto cvt = [&](const float* in, bf16* out, long n) {
    int n8 = (int)(n/8);
    int blocks = (n8 + 255)/256; if (blocks > 2048) blocks = 2048;
    cvt_kernel<<<blocks, 256, 0, stream>>>(in, out, n8);
  };
  cvt(Wq, wqkvb, (long)NC*NC);
  cvt(Wk, wqkvb + (long)NC*NC, (long)NC*NC);
  cvt(Wv, wqkvb + (long)2*NC*NC, (long)NC*NC);
  cvt(W1, w1b, (long)4*NC*NC);
  cvt(W2, w2b, (long)4*NC*NC);
  cvt(Wlm, wlmb, (long)NV*NC);

  embed_ln_kernel<<<NROWS, 64, 0, stream>>>(idx, tok, pos, g1, be1, x0, h1b);

  // fused QKV
  gemm256<EPI_BF16><<<dim3(6,32,1), 512, SMEM_B, stream>>>(
      h1b, wqkvb, 8, NC, NC, 0, 0, nullptr, qkvb, 3*NC, 0,
      nullptr, nullptr, 0, 0);

  transpose_kernel<<<dim3(NT/64, NC/64, NB), 256, 0, stream>>>(qkvb + 2*NC, 3*NC, vtb);

  // S = q k^T (per batch), causal block skip
  gemm256<EPI_F32,true><<<dim3(8,8,NB), 512, SMEM_B, stream>>>(
      qkvb, qkvb + NC, 8, 3*NC, 3*NC, (long)NT*3*NC, (long)NT*3*NC,
      Sb, nullptr, NT, (long)NT*NT,
      nullptr, nullptr, 0, 0);

  softmax_kernel<<<NROWS, 256, 0, stream>>>(Sb);

  // PV split-K over kv chunks: z = c*4 + b; partials -> pvp[z]
  gemm256<EPI_F32,false,false,true><<<dim3(2,8,16), 512, SMEM_B, stream>>>(
      (const bf16*)Sb, vtb, 8, 2*NT, NT, (long)NT*2*NT, (long)NC*NT,
      pvp, nullptr, NC, (long)NT*NC,
      nullptr, nullptr, 0, 0);

  // x1 = x0 + sum_c pvp; h2 = LN2(x1)
  pv_combine_ln_kernel<<<NROWS, 64, 0, stream>>>(pvp, x0, g2, be2, x1, h2b);

  // ff = relu(h2 W1^T + b1)
  gemm256<EPI_BIAS_RELU_BF16,false,true><<<dim3(32,8,1), 512, SMEM_B, stream>>>(
      h2b, w1b, 8, NC, NC, 0, 0, nullptr, ffb, 4*NC, 0,
      b1, nullptr, 0, 0);

  // FFN2 split-K x4
  gemm256<EPI_F32><<<dim3(2,32,4), 512, SMEM_B, stream>>>(
      ffb, w2b, 8, 4*NC, 4*NC, 512, 512,
      ff2p, nullptr, NC, (long)NROWS*NC,
      nullptr, nullptr, 0, 0);

  ffn2_combine_kernel<<<NROWS, 64, 0, stream>>>(ff2p, x1, b2, x2b);

  // LM head: BK=32 dbuf, 4 blocks/CU, LDS-transposed full-line stores
  lmhead128<<<dim3(64, NV/128), 256, 0, stream>>>(x2b, wlmb, blm, logits, pmax, psum);

  loss1_kernel<<<NROWS, 512, 0, stream>>>(pmax, psum, logits, tgt, rowloss);
  loss2_kernel<<<1, 256, 0, stream>>>(rowloss, loss);
}